// Round 2
// baseline (251.211 us; speedup 1.0000x reference)
//
#include <hip/hip_runtime.h>
#include <hip/hip_bf16.h>
#include <cstdint>
#include <cstddef>

constexpr int CB  = 8;
constexpr int CS  = 2048;
constexpr int CH  = 256;
constexpr int CNH = 4;
constexpr int CDH = 64;
constexpr int CT  = CB * CS;   // 16384 tokens

typedef __attribute__((ext_vector_type(8))) __bf16 bf16x8;
typedef __attribute__((ext_vector_type(4))) float  f32x4;

__device__ __forceinline__ float b2f(unsigned short u) {
    union { float f; unsigned int i; } v; v.i = ((unsigned int)u) << 16; return v.f;
}
__device__ __forceinline__ unsigned short f2b(float f) {
    union { float f; unsigned int i; } v; v.f = f;
    unsigned int r = v.i + 0x7FFFu + ((v.i >> 16) & 1u);
    return (unsigned short)(r >> 16);
}
__device__ __forceinline__ f32x4 mfma16(bf16x8 a, bf16x8 b, f32x4 c) {
    return __builtin_amdgcn_mfma_f32_16x16x32_bf16(a, b, c, 0, 0, 0);
}

#define GLOAD_LDS16(gptr, lptr)                                                        \
    __builtin_amdgcn_global_load_lds((const __attribute__((address_space(1))) void*)(gptr), \
                                     (__attribute__((address_space(3))) void*)(lptr), 16, 0, 0)

// ---------------- dtype detect: reading f32 data as bf16 yields huge/NaN values ----
__global__ __launch_bounds__(256) void detect_kernel(
    const unsigned short* __restrict__ h, int* __restrict__ flag)
{
    __shared__ int s_bad;
    const int tid = threadIdx.x;
    if (tid == 0) s_bad = 0;
    __syncthreads();
    bool bad = false;
    for (int i = tid; i < 2048; i += 256) {
        float v = b2f(h[i]);
        if (!(fabsf(v) < 1e25f)) bad = true;   // NaN also lands here
    }
    if (bad) s_bad = 1;
    __syncthreads();
    if (tid == 0) *flag = s_bad;               // 1 => buffers are f32, 0 => bf16
}

// ---------------- converters (runtime input dtype via flag) -----------------------
struct CvtArgs6  { const void* src[6];  void* dst[6];  int n[6]; };
struct CvtArgs11 { const void* src[11]; void* dst[11]; int n[11]; };

__global__ __launch_bounds__(256) void cvt_to_bf16_k(const int* __restrict__ flag, CvtArgs6 a)
{
    const int seg = blockIdx.y, n = a.n[seg];
    const bool inf32 = (*flag != 0);
    const float* sf = (const float*)a.src[seg];
    const unsigned short* sb = (const unsigned short*)a.src[seg];
    unsigned short* d = (unsigned short*)a.dst[seg];
    for (int i = (blockIdx.x * 256 + threadIdx.x) * 4; i < n; i += gridDim.x * 1024) {
        ushort4 o;
        if (inf32) {
            float4 v = *(const float4*)(sf + i);
            o.x = f2b(v.x); o.y = f2b(v.y); o.z = f2b(v.z); o.w = f2b(v.w);
        } else {
            o = *(const ushort4*)(sb + i);
        }
        *(ushort4*)(d + i) = o;
    }
}

__global__ __launch_bounds__(256) void cvt_to_f32_k(const int* __restrict__ flag, CvtArgs11 a)
{
    const int seg = blockIdx.y, n = a.n[seg];
    const bool inf32 = (*flag != 0);
    const float* sf = (const float*)a.src[seg];
    const unsigned short* sb = (const unsigned short*)a.src[seg];
    float* d = (float*)a.dst[seg];
    for (int i = (blockIdx.x * 256 + threadIdx.x) * 4; i < n; i += gridDim.x * 1024) {
        float4 o;
        if (inf32) {
            o = *(const float4*)(sf + i);
        } else {
            ushort4 v = *(const ushort4*)(sb + i);
            o.x = b2f(v.x); o.y = b2f(v.y); o.z = b2f(v.z); o.w = b2f(v.w);
        }
        *(float4*)(d + i) = o;
    }
}

// ---------------- LayerNorm: one wave per token (H=256, 4 f32/lane) ---------------
__global__ __launch_bounds__(256) void ln_kernel(
    const float* __restrict__ x, const float* __restrict__ w,
    const float* __restrict__ b, unsigned short* __restrict__ out)
{
    const int wave = threadIdx.x >> 6, lane = threadIdx.x & 63;
    const int token = blockIdx.x * 4 + wave;
    const int c = lane * 4;
    const size_t rowo = (size_t)token * CH + c;
    float4 u = *(const float4*)(x + rowo);
    float v0 = u.x, v1 = u.y, v2 = u.z, v3 = u.w;
    float s = v0 + v1 + v2 + v3;
    float q = v0*v0 + v1*v1 + v2*v2 + v3*v3;
    #pragma unroll
    for (int m = 1; m < 64; m <<= 1) { s += __shfl_xor(s, m, 64); q += __shfl_xor(q, m, 64); }
    float mean = s * (1.0f/256.0f);
    float var  = q * (1.0f/256.0f) - mean*mean;
    float inv  = rsqrtf(var + 1e-12f);
    float4 ww = *(const float4*)(w + c);
    float4 bb = *(const float4*)(b + c);
    ushort4 o;
    o.x = f2b(ww.x * (v0-mean)*inv + bb.x);
    o.y = f2b(ww.y * (v1-mean)*inv + bb.y);
    o.z = f2b(ww.z * (v2-mean)*inv + bb.z);
    o.w = f2b(ww.w * (v3-mean)*inv + bb.w);
    *(ushort4*)(out + rowo) = o;
}

// ---------------- Generic 128x128 bf16 MFMA GEMM: C = act(A @ W^T + bias) ---------
// A: [M][K] bf16, W: [N][K] bf16 row-major. bias/resid f32. 4 waves, 64x64 each.
template<bool GELU, bool RESID, bool HEADSTORE, bool OUTF32, bool OUTDYN>
__device__ __forceinline__ void gemm_core(
    const unsigned short* __restrict__ A, const unsigned short* __restrict__ W,
    const float* __restrict__ bias, const float* __restrict__ resid,
    void* __restrict__ out, const int* __restrict__ flag,
    int K, int N, int m0, int n0)
{
    __shared__ __align__(16) unsigned short lA[128*32];
    __shared__ __align__(16) unsigned short lB[128*32];
    const int tid  = threadIdx.x;
    const int lane = tid & 63;
    const int wave = tid >> 6;
    const int wr = (wave >> 1) * 64;
    const int wc = (wave & 1) * 64;
    const int g = lane >> 4, r16 = lane & 15;
    const int lrow = lane >> 2;        // 0..15 rows within 1KB chunk
    const int lch  = lane & 3;         // 16B chunk within 64B row

    const f32x4 zero = {0.f, 0.f, 0.f, 0.f};
    f32x4 acc[4][4];
    #pragma unroll
    for (int m = 0; m < 4; ++m)
        #pragma unroll
        for (int n = 0; n < 4; ++n) acc[m][n] = zero;

    for (int k0 = 0; k0 < K; k0 += 32) {
        #pragma unroll
        for (int i = 0; i < 2; ++i) {
            int chunk = wave + i * 4;              // 0..7 (1KB chunks of 8KB tile)
            int row = chunk * 16 + lrow;           // tile row
            const unsigned short* ga = A + (size_t)(m0 + row) * K + k0 + lch * 8;
            GLOAD_LDS16(ga, &lA[chunk * 512]);
            const unsigned short* gw = W + (size_t)(n0 + row) * K + k0 + lch * 8;
            GLOAD_LDS16(gw, &lB[chunk * 512]);
        }
        __syncthreads();
        bf16x8 af[4], wf[4];
        #pragma unroll
        for (int m = 0; m < 4; ++m) af[m] = *(const bf16x8*)&lA[(wr + m*16 + r16) * 32 + g * 8];
        #pragma unroll
        for (int n = 0; n < 4; ++n) wf[n] = *(const bf16x8*)&lB[(wc + n*16 + r16) * 32 + g * 8];
        #pragma unroll
        for (int m = 0; m < 4; ++m)
            #pragma unroll
            for (int n = 0; n < 4; ++n)
                acc[m][n] = mfma16(af[m], wf[n], acc[m][n]);
        __syncthreads();
    }

    const bool of32dyn = OUTDYN ? (*flag != 0) : false;
    #pragma unroll
    for (int n = 0; n < 4; ++n) {
        int col = n0 + wc + n*16 + r16;
        float bv = bias[col];
        #pragma unroll
        for (int m = 0; m < 4; ++m) {
            int row0 = m0 + wr + m*16 + g*4;
            #pragma unroll
            for (int r = 0; r < 4; ++r) {
                int row = row0 + r;
                float v = acc[m][n][r] + bv;
                if (GELU) {
                    float a = 0.79788456080286541f * (v + 0.044715f * v * v * v);
                    v = v * (1.0f / (1.0f + __expf(-2.0f * a)));   // 0.5v(1+tanh(a))
                }
                if (RESID) v += resid[(size_t)row * N + col];
                size_t oidx;
                if (HEADSTORE) {
                    int hh = col >> 6, d = col & 63;
                    int bb = row >> 11, ss = row & 2047;
                    oidx = ((((size_t)bb * CNH + hh) * CS) + ss) * CDH + d;
                } else {
                    oidx = (size_t)row * N + col;
                }
                if (OUTF32)      ((float*)out)[oidx] = v;
                else if (OUTDYN) {
                    if (of32dyn) ((float*)out)[oidx] = v;
                    else         ((unsigned short*)out)[oidx] = f2b(v);
                }
                else             ((unsigned short*)out)[oidx] = f2b(v);
            }
        }
    }
}

__global__ __launch_bounds__(256) void k_qkv(
    const unsigned short* __restrict__ xhat,
    const unsigned short* Wq, const float* bq, unsigned short* q,
    const unsigned short* Wk, const float* bk, unsigned short* k,
    const unsigned short* Wv, const float* bv, unsigned short* v)
{
    const unsigned short* W  = blockIdx.z == 0 ? Wq : (blockIdx.z == 1 ? Wk : Wv);
    const float*          bi = blockIdx.z == 0 ? bq : (blockIdx.z == 1 ? bk : bv);
    unsigned short*       o  = blockIdx.z == 0 ? q  : (blockIdx.z == 1 ? k  : v);
    gemm_core<false, false, true, false, false>(xhat, W, bi, nullptr, o, nullptr,
                                                CH, CH, blockIdx.x * 128, blockIdx.y * 128);
}

__global__ __launch_bounds__(256) void k_oproj(
    const unsigned short* __restrict__ A, const unsigned short* __restrict__ W,
    const float* __restrict__ bias, const float* __restrict__ resid,
    float* __restrict__ out)
{
    gemm_core<false, true, false, true, false>(A, W, bias, resid, out, nullptr,
                                               CH, CH, blockIdx.x * 128, blockIdx.y * 128);
}

__global__ __launch_bounds__(256) void k_ffn1(
    const unsigned short* __restrict__ A, const unsigned short* __restrict__ W,
    const float* __restrict__ bias, unsigned short* __restrict__ out)
{
    gemm_core<true, false, false, false, false>(A, W, bias, nullptr, out, nullptr,
                                                CH, 4*CH, blockIdx.x * 128, blockIdx.y * 128);
}

__global__ __launch_bounds__(256) void k_ffn2(
    const unsigned short* __restrict__ A, const unsigned short* __restrict__ W,
    const float* __restrict__ bias, const float* __restrict__ resid,
    void* __restrict__ out, const int* __restrict__ flag)
{
    gemm_core<false, true, false, false, true>(A, W, bias, resid, out, flag,
                                               4*CH, CH, blockIdx.x * 128, blockIdx.y * 128);
}

// ---------------- Flash attention: block = (128-query tile, b*NH+h) ---------------
__global__ __launch_bounds__(256) void attn_kernel(
    const unsigned short* __restrict__ Q, const unsigned short* __restrict__ Kp,
    const unsigned short* __restrict__ V, const int* __restrict__ mask,
    unsigned short* __restrict__ out)
{
    __shared__ __align__(16) unsigned short Qs[128 * 72];
    __shared__ __align__(16) unsigned short Ks[64 * 72];
    __shared__ __align__(16) unsigned short Vt[64 * 72];
    __shared__ __align__(16) unsigned short Ps[128 * 72];
    __shared__ int mrow[128];

    const int tid = threadIdx.x, lane = tid & 63, wave = tid >> 6;
    const int bh = blockIdx.y;
    const int bb = bh >> 2, hh = bh & 3;
    const int q0 = blockIdx.x * 128;
    const size_t base = (size_t)bh * CS * CDH;

    #pragma unroll
    for (int i = 0; i < 4; ++i) {                  // Q tile: 128 x 64 -> 1024 16B tasks
        int t2 = tid + i * 256;
        int row = t2 >> 3, ch = t2 & 7;
        uint4 dv = *(const uint4*)(Q + base + (size_t)(q0 + row) * CDH + ch * 8);
        *(uint4*)&Qs[row * 72 + ch * 8] = dv;
    }
    if (tid < 128) mrow[tid] = mask[bb * CS + q0 + tid];

    const int g = lane >> 4, r16 = lane & 15;
    const int wq = wave * 32;
    const f32x4 zero = {0.f, 0.f, 0.f, 0.f};
    f32x4 o_acc[2][4];
    float m_run[2][4], l_run[2][4];
    #pragma unroll
    for (int m = 0; m < 2; ++m) {
        #pragma unroll
        for (int n = 0; n < 4; ++n) o_acc[m][n] = zero;
        #pragma unroll
        for (int r = 0; r < 4; ++r) { m_run[m][r] = -1e30f; l_run[m][r] = 0.f; }
    }
    const int vrow = tid & 63;
    const int vch  = tid >> 6;

    for (int kt = 0; kt < CS; kt += 64) {
        #pragma unroll
        for (int i = 0; i < 2; ++i) {              // K tile: 64 x 64
            int t2 = tid + i * 256;
            int row = t2 >> 3, ch = t2 & 7;
            uint4 dv = *(const uint4*)(Kp + base + (size_t)(kt + row) * CDH + ch * 8);
            *(uint4*)&Ks[row * 72 + ch * 8] = dv;
        }
        #pragma unroll
        for (int i = 0; i < 2; ++i) {              // V transposed: Vt[d][k_local]
            int ch = vch + i * 4;
            unsigned short tmp[8];
            *(uint4*)tmp = *(const uint4*)(V + base + (size_t)(kt + vrow) * CDH + ch * 8);
            #pragma unroll
            for (int j = 0; j < 8; ++j) Vt[(ch * 8 + j) * 72 + vrow] = tmp[j];
        }
        __syncthreads();

        f32x4 s_acc[2][4];
        #pragma unroll
        for (int m = 0; m < 2; ++m)
            #pragma unroll
            for (int n = 0; n < 4; ++n) s_acc[m][n] = zero;
        #pragma unroll
        for (int kk = 0; kk < 2; ++kk) {
            bf16x8 aq[2], bk2[4];
            #pragma unroll
            for (int m = 0; m < 2; ++m)
                aq[m] = *(const bf16x8*)&Qs[(wq + m*16 + r16) * 72 + kk * 32 + g * 8];
            #pragma unroll
            for (int n = 0; n < 4; ++n)
                bk2[n] = *(const bf16x8*)&Ks[(n*16 + r16) * 72 + kk * 32 + g * 8];
            #pragma unroll
            for (int m = 0; m < 2; ++m)
                #pragma unroll
                for (int n = 0; n < 4; ++n)
                    s_acc[m][n] = mfma16(aq[m], bk2[n], s_acc[m][n]);
        }

        // online softmax (row rloc spans the 16 lanes sharing g; xor 1,2,4,8)
        #pragma unroll
        for (int m = 0; m < 2; ++m) {
            #pragma unroll
            for (int r = 0; r < 4; ++r) {
                int rloc = wq + m*16 + g*4 + r;
                bool msk = (mrow[rloc] == 0);
                float sv[4]; float vmax = -1e30f;
                #pragma unroll
                for (int n = 0; n < 4; ++n) {
                    float x = msk ? 0.f : s_acc[m][n][r] * 0.125f;
                    sv[n] = x; vmax = fmaxf(vmax, x);
                }
                #pragma unroll
                for (int d = 1; d < 16; d <<= 1) vmax = fmaxf(vmax, __shfl_xor(vmax, d, 64));
                float mnew = fmaxf(m_run[m][r], vmax);
                float corr = __expf(m_run[m][r] - mnew);
                float psum = 0.f;
                #pragma unroll
                for (int n = 0; n < 4; ++n) {
                    float p = __expf(sv[n] - mnew);
                    psum += p;
                    Ps[rloc * 72 + n*16 + r16] = f2b(p);
                }
                #pragma unroll
                for (int d = 1; d < 16; d <<= 1) psum += __shfl_xor(psum, d, 64);
                l_run[m][r] = l_run[m][r] * corr + psum;
                m_run[m][r] = mnew;
                #pragma unroll
                for (int n = 0; n < 4; ++n) o_acc[m][n][r] *= corr;
            }
        }
        __syncthreads();

        #pragma unroll
        for (int kk = 0; kk < 2; ++kk) {            // O += P @ V
            bf16x8 ap[2], bv2[4];
            #pragma unroll
            for (int m = 0; m < 2; ++m)
                ap[m] = *(const bf16x8*)&Ps[(wq + m*16 + r16) * 72 + kk * 32 + g * 8];
            #pragma unroll
            for (int n = 0; n < 4; ++n)
                bv2[n] = *(const bf16x8*)&Vt[(n*16 + r16) * 72 + kk * 32 + g * 8];
            #pragma unroll
            for (int m = 0; m < 2; ++m)
                #pragma unroll
                for (int n = 0; n < 4; ++n)
                    o_acc[m][n] = mfma16(ap[m], bv2[n], o_acc[m][n]);
        }
        __syncthreads();                            // protect Ks/Vt for next tile
    }

    #pragma unroll
    for (int m = 0; m < 2; ++m) {
        #pragma unroll
        for (int r = 0; r < 4; ++r) {
            int rloc = wq + m*16 + g*4 + r;
            float inv = 1.0f / l_run[m][r];
            int srow = q0 + rloc;
            #pragma unroll
            for (int n = 0; n < 4; ++n)
                out[((size_t)(bb * CS + srow)) * CH + hh * CDH + n*16 + r16] =
                    f2b(o_acc[m][n][r] * inv);
        }
    }
}

// ----------------------------------------------------------------------------------
extern "C" void kernel_launch(void* const* d_in, const int* in_sizes, int n_in,
                              void* d_out, int out_size, void* d_ws, size_t ws_size,
                              hipStream_t stream)
{
    const void* hidden = d_in[0];
    const void* Wq = d_in[1];  const void* bq = d_in[2];
    const void* Wk = d_in[3];  const void* bk = d_in[4];
    const void* Wv = d_in[5];  const void* bv = d_in[6];
    const void* Wo = d_in[7];  const void* bo = d_in[8];
    const void* W1 = d_in[9];  const void* b1 = d_in[10];
    const void* W2 = d_in[11]; const void* b2 = d_in[12];
    const void* ln1w = d_in[13]; const void* ln1b = d_in[14];
    const void* ln2w = d_in[15]; const void* ln2b = d_in[16];
    const int* mask = (const int*)d_in[17];

    char* ws = (char*)d_ws;
    const size_t KB = 1u << 10, MB = 1u << 20;
    int*            flag  = (int*)ws;
    float*          bqf   = (float*)(ws + 4*KB);
    float*          bkf   = (float*)(ws + 8*KB);
    float*          bvf   = (float*)(ws + 12*KB);
    float*          bof   = (float*)(ws + 16*KB);
    float*          b1f   = (float*)(ws + 20*KB);
    float*          b2f_  = (float*)(ws + 28*KB);
    float*          ln1wf = (float*)(ws + 32*KB);
    float*          ln1bf = (float*)(ws + 36*KB);
    float*          ln2wf = (float*)(ws + 40*KB);
    float*          ln2bf = (float*)(ws + 44*KB);
    unsigned short* Wqb   = (unsigned short*)(ws + 1*MB);
    unsigned short* Wkb   = (unsigned short*)(ws + 1*MB + 256*KB);
    unsigned short* Wvb   = (unsigned short*)(ws + 1*MB + 512*KB);
    unsigned short* Wob   = (unsigned short*)(ws + 1*MB + 768*KB);
    unsigned short* W1b   = (unsigned short*)(ws + 2*MB);
    unsigned short* W2b   = (unsigned short*)(ws + 2*MB + 512*KB);
    float*          hf32  = (float*)(ws + 3*MB);            // [T][H] f32, 16MB
    unsigned short* xhat  = (unsigned short*)(ws + 19*MB);  // 8MB
    unsigned short* qb    = (unsigned short*)(ws + 27*MB);  // 8MB
    unsigned short* kb    = (unsigned short*)(ws + 35*MB);  // 8MB
    unsigned short* vb    = (unsigned short*)(ws + 43*MB);  // 8MB
    unsigned short* attnb = xhat;                           // xhat dead after QKV
    float*          hid2f = (float*)(ws + 35*MB);           // 16MB over kb+vb (dead)
    unsigned short* yhat  = qb;                             // qb dead after attn
    unsigned short* h1g   = (unsigned short*)(ws + 51*MB);  // [T][1024] bf16, 32MB

    dim3 blk(256);
    detect_kernel<<<1, blk, 0, stream>>>((const unsigned short*)hidden, flag);

    CvtArgs6 cw;
    cw.src[0]=Wq;  cw.dst[0]=Wqb; cw.n[0]=CH*CH;
    cw.src[1]=Wk;  cw.dst[1]=Wkb; cw.n[1]=CH*CH;
    cw.src[2]=Wv;  cw.dst[2]=Wvb; cw.n[2]=CH*CH;
    cw.src[3]=Wo;  cw.dst[3]=Wob; cw.n[3]=CH*CH;
    cw.src[4]=W1;  cw.dst[4]=W1b; cw.n[4]=4*CH*CH;
    cw.src[5]=W2;  cw.dst[5]=W2b; cw.n[5]=4*CH*CH;
    cvt_to_bf16_k<<<dim3(64, 6), blk, 0, stream>>>(flag, cw);

    CvtArgs11 cf;
    cf.src[0]=hidden; cf.dst[0]=hf32;  cf.n[0]=CT*CH;
    cf.src[1]=bq;     cf.dst[1]=bqf;   cf.n[1]=CH;
    cf.src[2]=bk;     cf.dst[2]=bkf;   cf.n[2]=CH;
    cf.src[3]=bv;     cf.dst[3]=bvf;   cf.n[3]=CH;
    cf.src[4]=bo;     cf.dst[4]=bof;   cf.n[4]=CH;
    cf.src[5]=b1;     cf.dst[5]=b1f;   cf.n[5]=4*CH;
    cf.src[6]=b2;     cf.dst[6]=b2f_;  cf.n[6]=CH;
    cf.src[7]=ln1w;   cf.dst[7]=ln1wf; cf.n[7]=CH;
    cf.src[8]=ln1b;   cf.dst[8]=ln1bf; cf.n[8]=CH;
    cf.src[9]=ln2w;   cf.dst[9]=ln2wf; cf.n[9]=CH;
    cf.src[10]=ln2b;  cf.dst[10]=ln2bf;cf.n[10]=CH;
    cvt_to_f32_k<<<dim3(512, 11), blk, 0, stream>>>(flag, cf);

    ln_kernel<<<CT / 4, blk, 0, stream>>>(hf32, ln1wf, ln1bf, xhat);
    k_qkv<<<dim3(CT / 128, CH / 128, 3), blk, 0, stream>>>(xhat, Wqb, bqf, qb,
                                                           Wkb, bkf, kb, Wvb, bvf, vb);
    attn_kernel<<<dim3(CS / 128, CB * CNH), blk, 0, stream>>>(qb, kb, vb, mask, attnb);
    k_oproj<<<dim3(CT / 128, CH / 128), blk, 0, stream>>>(attnb, Wob, bof, hf32, hid2f);
    ln_kernel<<<CT / 4, blk, 0, stream>>>(hid2f, ln2wf, ln2bf, yhat);
    k_ffn1<<<dim3(CT / 128, (4 * CH) / 128), blk, 0, stream>>>(yhat, W1b, b1f, h1g);
    k_ffn2<<<dim3(CT / 128, CH / 128), blk, 0, stream>>>(h1g, W2b, b2f_, hid2f,
                                                         d_out, flag);
}

// Round 3
// 216.513 us; speedup vs baseline: 1.1603x; 1.1603x over previous
//
#include <hip/hip_runtime.h>
#include <hip/hip_bf16.h>
#include <cstdint>
#include <cstddef>

constexpr int CB  = 8;
constexpr int CS  = 2048;
constexpr int CH  = 256;
constexpr int CNH = 4;
constexpr int CDH = 64;
constexpr int CT  = CB * CS;   // 16384 tokens

typedef __attribute__((ext_vector_type(8))) __bf16 bf16x8;
typedef __attribute__((ext_vector_type(4))) float  f32x4;

__device__ __forceinline__ float b2f(unsigned short u) {
    union { float f; unsigned int i; } v; v.i = ((unsigned int)u) << 16; return v.f;
}
__device__ __forceinline__ unsigned short f2b(float f) {
    union { float f; unsigned int i; } v; v.f = f;
    unsigned int r = v.i + 0x7FFFu + ((v.i >> 16) & 1u);
    return (unsigned short)(r >> 16);
}
__device__ __forceinline__ f32x4 mfma16(bf16x8 a, bf16x8 b, f32x4 c) {
    return __builtin_amdgcn_mfma_f32_16x16x32_bf16(a, b, c, 0, 0, 0);
}

#define GLOAD_LDS16(gptr, lptr)                                                        \
    __builtin_amdgcn_global_load_lds((const __attribute__((address_space(1))) void*)(gptr), \
                                     (__attribute__((address_space(3))) void*)(lptr), 16, 0, 0)

// ---------------- dtype detect: reading f32 data as bf16 yields huge/NaN values ----
__global__ __launch_bounds__(256) void detect_kernel(
    const unsigned short* __restrict__ h, int* __restrict__ flag)
{
    __shared__ int s_bad;
    const int tid = threadIdx.x;
    if (tid == 0) s_bad = 0;
    __syncthreads();
    bool bad = false;
    for (int i = tid; i < 2048; i += 256) {
        float v = b2f(h[i]);
        if (!(fabsf(v) < 1e25f)) bad = true;   // NaN also lands here
    }
    if (bad) s_bad = 1;
    __syncthreads();
    if (tid == 0) *flag = s_bad;               // 1 => buffers are f32, 0 => bf16
}

// ---------------- converters (runtime input dtype via flag) -----------------------
struct CvtArgs6  { const void* src[6];  void* dst[6];  int n[6]; };
struct CvtArgs11 { const void* src[11]; void* dst[11]; int n[11]; };

__global__ __launch_bounds__(256) void cvt_to_bf16_k(const int* __restrict__ flag, CvtArgs6 a)
{
    const int seg = blockIdx.y, n = a.n[seg];
    const bool inf32 = (*flag != 0);
    const float* sf = (const float*)a.src[seg];
    const unsigned short* sb = (const unsigned short*)a.src[seg];
    unsigned short* d = (unsigned short*)a.dst[seg];
    for (int i = (blockIdx.x * 256 + threadIdx.x) * 4; i < n; i += gridDim.x * 1024) {
        ushort4 o;
        if (inf32) {
            float4 v = *(const float4*)(sf + i);
            o.x = f2b(v.x); o.y = f2b(v.y); o.z = f2b(v.z); o.w = f2b(v.w);
        } else {
            o = *(const ushort4*)(sb + i);
        }
        *(ushort4*)(d + i) = o;
    }
}

__global__ __launch_bounds__(256) void cvt_to_f32_k(const int* __restrict__ flag, CvtArgs11 a)
{
    const int seg = blockIdx.y, n = a.n[seg];
    const bool inf32 = (*flag != 0);
    const float* sf = (const float*)a.src[seg];
    const unsigned short* sb = (const unsigned short*)a.src[seg];
    float* d = (float*)a.dst[seg];
    for (int i = (blockIdx.x * 256 + threadIdx.x) * 4; i < n; i += gridDim.x * 1024) {
        float4 o;
        if (inf32) {
            o = *(const float4*)(sf + i);
        } else {
            ushort4 v = *(const ushort4*)(sb + i);
            o.x = b2f(v.x); o.y = b2f(v.y); o.z = b2f(v.z); o.w = b2f(v.w);
        }
        *(float4*)(d + i) = o;
    }
}

// ---------------- LayerNorm: one wave per token (H=256, 4 f32/lane) ---------------
__global__ __launch_bounds__(256) void ln_kernel(
    const float* __restrict__ x, const float* __restrict__ w,
    const float* __restrict__ b, unsigned short* __restrict__ out)
{
    const int wave = threadIdx.x >> 6, lane = threadIdx.x & 63;
    const int token = blockIdx.x * 4 + wave;
    const int c = lane * 4;
    const size_t rowo = (size_t)token * CH + c;
    float4 u = *(const float4*)(x + rowo);
    float v0 = u.x, v1 = u.y, v2 = u.z, v3 = u.w;
    float s = v0 + v1 + v2 + v3;
    float q = v0*v0 + v1*v1 + v2*v2 + v3*v3;
    #pragma unroll
    for (int m = 1; m < 64; m <<= 1) { s += __shfl_xor(s, m, 64); q += __shfl_xor(q, m, 64); }
    float mean = s * (1.0f/256.0f);
    float var  = q * (1.0f/256.0f) - mean*mean;
    float inv  = rsqrtf(var + 1e-12f);
    float4 ww = *(const float4*)(w + c);
    float4 bb = *(const float4*)(b + c);
    ushort4 o;
    o.x = f2b(ww.x * (v0-mean)*inv + bb.x);
    o.y = f2b(ww.y * (v1-mean)*inv + bb.y);
    o.z = f2b(ww.z * (v2-mean)*inv + bb.z);
    o.w = f2b(ww.w * (v3-mean)*inv + bb.w);
    *(ushort4*)(out + rowo) = o;
}

// ---------------- Generic 128x128 bf16 MFMA GEMM: C = act(A @ W^T + bias) ---------
template<bool GELU, bool RESID, bool HEADSTORE, bool OUTF32, bool OUTDYN>
__device__ __forceinline__ void gemm_core(
    const unsigned short* __restrict__ A, const unsigned short* __restrict__ W,
    const float* __restrict__ bias, const float* __restrict__ resid,
    void* __restrict__ out, const int* __restrict__ flag,
    int K, int N, int m0, int n0)
{
    __shared__ __align__(16) unsigned short lA[128*32];
    __shared__ __align__(16) unsigned short lB[128*32];
    const int tid  = threadIdx.x;
    const int lane = tid & 63;
    const int wave = tid >> 6;
    const int wr = (wave >> 1) * 64;
    const int wc = (wave & 1) * 64;
    const int g = lane >> 4, r16 = lane & 15;
    const int lrow = lane >> 2;        // 0..15 rows within 1KB chunk
    const int lch  = lane & 3;         // 16B chunk within 64B row

    const f32x4 zero = {0.f, 0.f, 0.f, 0.f};
    f32x4 acc[4][4];
    #pragma unroll
    for (int m = 0; m < 4; ++m)
        #pragma unroll
        for (int n = 0; n < 4; ++n) acc[m][n] = zero;

    for (int k0 = 0; k0 < K; k0 += 32) {
        #pragma unroll
        for (int i = 0; i < 2; ++i) {
            int chunk = wave + i * 4;              // 0..7 (1KB chunks of 8KB tile)
            int row = chunk * 16 + lrow;           // tile row
            const unsigned short* ga = A + (size_t)(m0 + row) * K + k0 + lch * 8;
            GLOAD_LDS16(ga, &lA[chunk * 512]);
            const unsigned short* gw = W + (size_t)(n0 + row) * K + k0 + lch * 8;
            GLOAD_LDS16(gw, &lB[chunk * 512]);
        }
        __syncthreads();
        bf16x8 af[4], wf[4];
        #pragma unroll
        for (int m = 0; m < 4; ++m) af[m] = *(const bf16x8*)&lA[(wr + m*16 + r16) * 32 + g * 8];
        #pragma unroll
        for (int n = 0; n < 4; ++n) wf[n] = *(const bf16x8*)&lB[(wc + n*16 + r16) * 32 + g * 8];
        #pragma unroll
        for (int m = 0; m < 4; ++m)
            #pragma unroll
            for (int n = 0; n < 4; ++n)
                acc[m][n] = mfma16(af[m], wf[n], acc[m][n]);
        __syncthreads();
    }

    const bool of32dyn = OUTDYN ? (*flag != 0) : false;
    #pragma unroll
    for (int n = 0; n < 4; ++n) {
        int col = n0 + wc + n*16 + r16;
        float bv = bias[col];
        #pragma unroll
        for (int m = 0; m < 4; ++m) {
            int row0 = m0 + wr + m*16 + g*4;
            #pragma unroll
            for (int r = 0; r < 4; ++r) {
                int row = row0 + r;
                float v = acc[m][n][r] + bv;
                if (GELU) {
                    float a = 0.79788456080286541f * (v + 0.044715f * v * v * v);
                    v = v * (1.0f / (1.0f + __expf(-2.0f * a)));   // 0.5v(1+tanh(a))
                }
                if (RESID) v += resid[(size_t)row * N + col];
                size_t oidx;
                if (HEADSTORE) {
                    int hh = col >> 6, d = col & 63;
                    int bb = row >> 11, ss = row & 2047;
                    oidx = ((((size_t)bb * CNH + hh) * CS) + ss) * CDH + d;
                } else {
                    oidx = (size_t)row * N + col;
                }
                if (OUTF32)      ((float*)out)[oidx] = v;
                else if (OUTDYN) {
                    if (of32dyn) ((float*)out)[oidx] = v;
                    else         ((unsigned short*)out)[oidx] = f2b(v);
                }
                else             ((unsigned short*)out)[oidx] = f2b(v);
            }
        }
    }
}

__global__ __launch_bounds__(256) void k_qkv(
    const unsigned short* __restrict__ xhat,
    const unsigned short* Wq, const float* bq, unsigned short* q,
    const unsigned short* Wk, const float* bk, unsigned short* k,
    const unsigned short* Wv, const float* bv, unsigned short* v)
{
    const unsigned short* W  = blockIdx.z == 0 ? Wq : (blockIdx.z == 1 ? Wk : Wv);
    const float*          bi = blockIdx.z == 0 ? bq : (blockIdx.z == 1 ? bk : bv);
    unsigned short*       o  = blockIdx.z == 0 ? q  : (blockIdx.z == 1 ? k  : v);
    gemm_core<false, false, true, false, false>(xhat, W, bi, nullptr, o, nullptr,
                                                CH, CH, blockIdx.x * 128, blockIdx.y * 128);
}

__global__ __launch_bounds__(256) void k_oproj(
    const unsigned short* __restrict__ A, const unsigned short* __restrict__ W,
    const float* __restrict__ bias, const float* __restrict__ resid,
    float* __restrict__ out)
{
    gemm_core<false, true, false, true, false>(A, W, bias, resid, out, nullptr,
                                               CH, CH, blockIdx.x * 128, blockIdx.y * 128);
}

__global__ __launch_bounds__(256) void k_ffn1(
    const unsigned short* __restrict__ A, const unsigned short* __restrict__ W,
    const float* __restrict__ bias, unsigned short* __restrict__ out)
{
    gemm_core<true, false, false, false, false>(A, W, bias, nullptr, out, nullptr,
                                                CH, 4*CH, blockIdx.x * 128, blockIdx.y * 128);
}

__global__ __launch_bounds__(256) void k_ffn2(
    const unsigned short* __restrict__ A, const unsigned short* __restrict__ W,
    const float* __restrict__ bias, const float* __restrict__ resid,
    void* __restrict__ out, const int* __restrict__ flag)
{
    gemm_core<false, true, false, false, true>(A, W, bias, resid, out, flag,
                                               4*CH, CH, blockIdx.x * 128, blockIdx.y * 128);
}

// ---------------- V transpose: [bh][S][DH] -> [bh][DH][S] -------------------------
__global__ __launch_bounds__(256) void vtrans_kernel(
    const unsigned short* __restrict__ v, unsigned short* __restrict__ vt)
{
    __shared__ unsigned short T[64 * 72];
    const int bh = blockIdx.y, s0 = blockIdx.x * 64, tid = threadIdx.x;
    const size_t ibase = (size_t)bh * CS * CDH;
    const size_t obase = (size_t)bh * CDH * CS;
    #pragma unroll
    for (int i = 0; i < 2; ++i) {
        int t2 = tid + i * 256;
        int row = t2 >> 3, ch = t2 & 7;          // row: s-local, ch: d-chunk
        uint4 dv = *(const uint4*)(v + ibase + (size_t)(s0 + row) * CDH + ch * 8);
        *(uint4*)&T[row * 72 + ch * 8] = dv;
    }
    __syncthreads();
    #pragma unroll
    for (int i = 0; i < 2; ++i) {
        int t2 = tid + i * 256;
        int d = t2 >> 3, ch = t2 & 7;            // d: out row, ch: s-chunk
        unsigned short tmp[8];
        #pragma unroll
        for (int j = 0; j < 8; ++j) tmp[j] = T[(ch * 8 + j) * 72 + d];
        *(uint4*)(vt + obase + (size_t)d * CS + s0 + ch * 8) = *(uint4*)tmp;
    }
}

// ---------------- Flash attention: 512 thr, 8 waves x 16 q-rows, KVBLK=64 ---------
// LDS rows are 64 bf16 (128B) linear, XOR-swizzled: byte ^= ((row&7)<<4).
__global__ __launch_bounds__(512, 4) void attn_kernel(
    const unsigned short* __restrict__ Q, const unsigned short* __restrict__ Kp,
    const unsigned short* __restrict__ Vt, const int* __restrict__ mask,
    unsigned short* __restrict__ out)
{
    __shared__ __align__(16) unsigned short Qs[128 * 64];
    __shared__ __align__(16) unsigned short Ks[64 * 64];
    __shared__ __align__(16) unsigned short Vs[64 * 64];
    __shared__ __align__(16) unsigned short Ps[128 * 64];
    __shared__ int mrow[128];

    const int tid = threadIdx.x, lane = tid & 63, wave = tid >> 6;
    const int bh = blockIdx.y, bb = bh >> 2, hh = bh & 3;
    const int q0 = blockIdx.x * 128;
    const size_t baseQ = (size_t)bh * CS * CDH;   // Q,K: [S][DH]
    const size_t baseT = (size_t)bh * CDH * CS;   // Vt:  [DH][S]

    const int g = lane >> 4, r16 = lane & 15;
    const int wq = wave * 16;
    const int swzA = (r16 & 7) << 4;              // frag-read swizzle (rows ≡ r16 mod 8)

    #pragma unroll
    for (int i = 0; i < 2; ++i) {                 // Q tile 128x64 -> 1024 16B tasks
        int t2 = tid + i * 512;
        int row = t2 >> 3, ch = t2 & 7;
        uint4 dv = *(const uint4*)(Q + baseQ + (size_t)(q0 + row) * CDH + ch * 8);
        *(uint4*)&Qs[row * 64 + (((ch * 16) ^ ((row & 7) << 4)) >> 1)] = dv;
    }
    if (tid < 128) mrow[tid] = mask[bb * CS + q0 + tid];

    f32x4 o_acc[4];
    float m_run[4], l_run[4];
    #pragma unroll
    for (int n = 0; n < 4; ++n) o_acc[n] = (f32x4){0.f, 0.f, 0.f, 0.f};
    #pragma unroll
    for (int r = 0; r < 4; ++r) { m_run[r] = -1e30f; l_run[r] = 0.f; }

    const int srow = tid >> 3, sch = tid & 7;     // staging coords (512 thr, one pass)
    const int sdst = srow * 64 + (((sch * 16) ^ ((srow & 7) << 4)) >> 1);

    uint4 kv = *(const uint4*)(Kp + baseQ + (size_t)srow * CDH + sch * 8);
    uint4 vv = *(const uint4*)(Vt + baseT + (size_t)srow * CS + sch * 8);

    for (int kt = 0; kt < CS; kt += 64) {
        *(uint4*)&Ks[sdst] = kv;
        *(uint4*)&Vs[sdst] = vv;
        __syncthreads();
        if (kt + 64 < CS) {                       // prefetch next tile (hides latency)
            kv = *(const uint4*)(Kp + baseQ + (size_t)(kt + 64 + srow) * CDH + sch * 8);
            vv = *(const uint4*)(Vt + baseT + (size_t)srow * CS + (kt + 64) + sch * 8);
        }

        f32x4 s_acc[4];
        #pragma unroll
        for (int n = 0; n < 4; ++n) s_acc[n] = (f32x4){0.f, 0.f, 0.f, 0.f};
        __builtin_amdgcn_s_setprio(1);
        #pragma unroll
        for (int kk = 0; kk < 2; ++kk) {
            bf16x8 aq = *(const bf16x8*)&Qs[(wq + r16) * 64 + (((kk*64 + g*16) ^ swzA) >> 1)];
            #pragma unroll
            for (int n = 0; n < 4; ++n) {
                bf16x8 bk2 = *(const bf16x8*)&Ks[(n*16 + r16) * 64 + (((kk*64 + g*16) ^ swzA) >> 1)];
                s_acc[n] = mfma16(aq, bk2, s_acc[n]);
            }
        }
        __builtin_amdgcn_s_setprio(0);

        // online softmax: row rloc spans 16 lanes (same g), xor 1,2,4,8 reduces
        #pragma unroll
        for (int r = 0; r < 4; ++r) {
            const int rloc = wq + g * 4 + r;
            const bool msk = (mrow[rloc] == 0);
            float sv[4]; float vmax = -1e30f;
            #pragma unroll
            for (int n = 0; n < 4; ++n) {
                float x = msk ? 0.f : s_acc[n][r] * 0.125f;
                sv[n] = x; vmax = fmaxf(vmax, x);
            }
            #pragma unroll
            for (int d = 1; d < 16; d <<= 1) vmax = fmaxf(vmax, __shfl_xor(vmax, d, 64));
            float mnew = fmaxf(m_run[r], vmax);
            float corr = __expf(m_run[r] - mnew);
            float psum = 0.f;
            const int pswz = (rloc & 7) << 4;
            #pragma unroll
            for (int n = 0; n < 4; ++n) {
                float p = __expf(sv[n] - mnew);
                psum += p;
                Ps[rloc * 64 + ((((n*16 + r16) * 2) ^ pswz) >> 1)] = f2b(p);
            }
            #pragma unroll
            for (int d = 1; d < 16; d <<= 1) psum += __shfl_xor(psum, d, 64);
            l_run[r] = l_run[r] * corr + psum;
            m_run[r] = mnew;
            #pragma unroll
            for (int n = 0; n < 4; ++n) o_acc[n][r] *= corr;
        }
        // no barrier needed: Ps rows are wave-exclusive; wave LDS ops are in-order

        __builtin_amdgcn_s_setprio(1);
        #pragma unroll
        for (int kk = 0; kk < 2; ++kk) {          // O += P @ V
            bf16x8 ap = *(const bf16x8*)&Ps[(wq + r16) * 64 + (((kk*64 + g*16) ^ swzA) >> 1)];
            #pragma unroll
            for (int n = 0; n < 4; ++n) {
                bf16x8 bv2 = *(const bf16x8*)&Vs[(n*16 + r16) * 64 + (((kk*64 + g*16) ^ swzA) >> 1)];
                o_acc[n] = mfma16(ap, bv2, o_acc[n]);
            }
        }
        __builtin_amdgcn_s_setprio(0);
        __syncthreads();                          // protect Ks/Vs before next staging
    }

    #pragma unroll
    for (int r = 0; r < 4; ++r) {
        const int rloc = wq + g * 4 + r;
        float inv = 1.0f / l_run[r];
        #pragma unroll
        for (int n = 0; n < 4; ++n)
            out[((size_t)(bb * CS + q0 + rloc)) * CH + hh * CDH + n*16 + r16] =
                f2b(o_acc[n][r] * inv);
    }
}

// ----------------------------------------------------------------------------------
extern "C" void kernel_launch(void* const* d_in, const int* in_sizes, int n_in,
                              void* d_out, int out_size, void* d_ws, size_t ws_size,
                              hipStream_t stream)
{
    const void* hidden = d_in[0];
    const void* Wq = d_in[1];  const void* bq = d_in[2];
    const void* Wk = d_in[3];  const void* bk = d_in[4];
    const void* Wv = d_in[5];  const void* bv = d_in[6];
    const void* Wo = d_in[7];  const void* bo = d_in[8];
    const void* W1 = d_in[9];  const void* b1 = d_in[10];
    const void* W2 = d_in[11]; const void* b2 = d_in[12];
    const void* ln1w = d_in[13]; const void* ln1b = d_in[14];
    const void* ln2w = d_in[15]; const void* ln2b = d_in[16];
    const int* mask = (const int*)d_in[17];

    char* ws = (char*)d_ws;
    const size_t KB = 1u << 10, MB = 1u << 20;
    int*            flag  = (int*)ws;
    float*          bqf   = (float*)(ws + 4*KB);
    float*          bkf   = (float*)(ws + 8*KB);
    float*          bvf   = (float*)(ws + 12*KB);
    float*          bof   = (float*)(ws + 16*KB);
    float*          b1f   = (float*)(ws + 20*KB);
    float*          b2f_  = (float*)(ws + 28*KB);
    float*          ln1wf = (float*)(ws + 32*KB);
    float*          ln1bf = (float*)(ws + 36*KB);
    float*          ln2wf = (float*)(ws + 40*KB);
    float*          ln2bf = (float*)(ws + 44*KB);
    unsigned short* Wqb   = (unsigned short*)(ws + 1*MB);
    unsigned short* Wkb   = (unsigned short*)(ws + 1*MB + 256*KB);
    unsigned short* Wvb   = (unsigned short*)(ws + 1*MB + 512*KB);
    unsigned short* Wob   = (unsigned short*)(ws + 1*MB + 768*KB);
    unsigned short* W1b   = (unsigned short*)(ws + 2*MB);
    unsigned short* W2b   = (unsigned short*)(ws + 2*MB + 512*KB);
    float*          hf32  = (float*)(ws + 3*MB);            // [T][H] f32, 16MB
    unsigned short* xhat  = (unsigned short*)(ws + 19*MB);  // 8MB
    unsigned short* qb    = (unsigned short*)(ws + 27*MB);  // 8MB
    unsigned short* kb    = (unsigned short*)(ws + 35*MB);  // 8MB
    unsigned short* vb    = (unsigned short*)(ws + 43*MB);  // 8MB
    unsigned short* attnb = xhat;                           // xhat dead after QKV
    float*          hid2f = (float*)(ws + 35*MB);           // 16MB over kb+vb (dead)
    unsigned short* vtb   = (unsigned short*)(ws + 51*MB);  // 8MB (pre-FFN lifetime)
    unsigned short* yhat  = qb;                             // qb dead after attn
    unsigned short* h1g   = (unsigned short*)(ws + 51*MB);  // [T][1024] bf16, 32MB

    dim3 blk(256);
    detect_kernel<<<1, blk, 0, stream>>>((const unsigned short*)hidden, flag);

    CvtArgs6 cw;
    cw.src[0]=Wq;  cw.dst[0]=Wqb; cw.n[0]=CH*CH;
    cw.src[1]=Wk;  cw.dst[1]=Wkb; cw.n[1]=CH*CH;
    cw.src[2]=Wv;  cw.dst[2]=Wvb; cw.n[2]=CH*CH;
    cw.src[3]=Wo;  cw.dst[3]=Wob; cw.n[3]=CH*CH;
    cw.src[4]=W1;  cw.dst[4]=W1b; cw.n[4]=4*CH*CH;
    cw.src[5]=W2;  cw.dst[5]=W2b; cw.n[5]=4*CH*CH;
    cvt_to_bf16_k<<<dim3(64, 6), blk, 0, stream>>>(flag, cw);

    CvtArgs11 cf;
    cf.src[0]=hidden; cf.dst[0]=hf32;  cf.n[0]=CT*CH;
    cf.src[1]=bq;     cf.dst[1]=bqf;   cf.n[1]=CH;
    cf.src[2]=bk;     cf.dst[2]=bkf;   cf.n[2]=CH;
    cf.src[3]=bv;     cf.dst[3]=bvf;   cf.n[3]=CH;
    cf.src[4]=bo;     cf.dst[4]=bof;   cf.n[4]=CH;
    cf.src[5]=b1;     cf.dst[5]=b1f;   cf.n[5]=4*CH;
    cf.src[6]=b2;     cf.dst[6]=b2f_;  cf.n[6]=CH;
    cf.src[7]=ln1w;   cf.dst[7]=ln1wf; cf.n[7]=CH;
    cf.src[8]=ln1b;   cf.dst[8]=ln1bf; cf.n[8]=CH;
    cf.src[9]=ln2w;   cf.dst[9]=ln2wf; cf.n[9]=CH;
    cf.src[10]=ln2b;  cf.dst[10]=ln2bf;cf.n[10]=CH;
    cvt_to_f32_k<<<dim3(512, 11), blk, 0, stream>>>(flag, cf);

    ln_kernel<<<CT / 4, blk, 0, stream>>>(hf32, ln1wf, ln1bf, xhat);
    k_qkv<<<dim3(CT / 128, CH / 128, 3), blk, 0, stream>>>(xhat, Wqb, bqf, qb,
                                                           Wkb, bkf, kb, Wvb, bvf, vb);
    vtrans_kernel<<<dim3(CS / 64, CB * CNH), blk, 0, stream>>>(vb, vtb);
    attn_kernel<<<dim3(CS / 128, CB * CNH), dim3(512), 0, stream>>>(qb, kb, vtb, mask, attnb);
    k_oproj<<<dim3(CT / 128, CH / 128), blk, 0, stream>>>(attnb, Wob, bof, hf32, hid2f);
    ln_kernel<<<CT / 4, blk, 0, stream>>>(hid2f, ln2wf, ln2bf, yhat);
    k_ffn1<<<dim3(CT / 128, (4 * CH) / 128), blk, 0, stream>>>(yhat, W1b, b1f, h1g);
    k_ffn2<<<dim3(CT / 128, CH / 128), blk, 0, stream>>>(h1g, W2b, b2f_, hid2f,
                                                         d_out, flag);
}

// Round 4
// 173.231 us; speedup vs baseline: 1.4501x; 1.2498x over previous
//
#include <hip/hip_runtime.h>
#include <hip/hip_bf16.h>
#include <cstdint>
#include <cstddef>

constexpr int CB  = 8;
constexpr int CS  = 2048;
constexpr int CH  = 256;
constexpr int CNH = 4;
constexpr int CDH = 64;
constexpr int CT  = CB * CS;   // 16384 tokens

typedef __attribute__((ext_vector_type(8))) __bf16 bf16x8;
typedef __attribute__((ext_vector_type(4))) float  f32x4;

__device__ __forceinline__ float b2f(unsigned short u) {
    union { float f; unsigned int i; } v; v.i = ((unsigned int)u) << 16; return v.f;
}
__device__ __forceinline__ unsigned short f2b(float f) {
    union { float f; unsigned int i; } v; v.f = f;
    unsigned int r = v.i + 0x7FFFu + ((v.i >> 16) & 1u);
    return (unsigned short)(r >> 16);
}
__device__ __forceinline__ unsigned short f2b_fast(float f) {  // round-half-up
    union { float f; unsigned int i; } v; v.f = f;
    return (unsigned short)((v.i + 0x8000u) >> 16);
}
__device__ __forceinline__ float fexp2(float x) {
#if __has_builtin(__builtin_amdgcn_exp2f)
    return __builtin_amdgcn_exp2f(x);
#else
    float r; asm("v_exp_f32 %0, %1" : "=v"(r) : "v"(x)); return r;
#endif
}
__device__ __forceinline__ f32x4 mfma16(bf16x8 a, bf16x8 b, f32x4 c) {
    return __builtin_amdgcn_mfma_f32_16x16x32_bf16(a, b, c, 0, 0, 0);
}

#define GLOAD_LDS16(gptr, lptr)                                                        \
    __builtin_amdgcn_global_load_lds((const __attribute__((address_space(1))) void*)(gptr), \
                                     (__attribute__((address_space(3))) void*)(lptr), 16, 0, 0)

// log2(e)/sqrt(DH): folded into Q projection so softmax uses raw exp2
#define QSCALE 0.1803368801111204f

// ---------------- dtype detect: reading f32 data as bf16 yields huge/NaN values ----
__global__ __launch_bounds__(256) void detect_kernel(
    const unsigned short* __restrict__ h, int* __restrict__ flag)
{
    __shared__ int s_bad;
    const int tid = threadIdx.x;
    if (tid == 0) s_bad = 0;
    __syncthreads();
    bool bad = false;
    for (int i = tid; i < 2048; i += 256) {
        float v = b2f(h[i]);
        if (!(fabsf(v) < 1e25f)) bad = true;   // NaN also lands here
    }
    if (bad) s_bad = 1;
    __syncthreads();
    if (tid == 0) *flag = s_bad;               // 1 => buffers are f32, 0 => bf16
}

// ---------------- converters (runtime input dtype via flag) -----------------------
struct CvtArgs6  { const void* src[6];  void* dst[6];  int n[6]; };
struct CvtArgs11 { const void* src[11]; void* dst[11]; int n[11]; };

__global__ __launch_bounds__(256) void cvt_to_bf16_k(const int* __restrict__ flag, CvtArgs6 a)
{
    const int seg = blockIdx.y, n = a.n[seg];
    const bool inf32 = (*flag != 0);
    const float* sf = (const float*)a.src[seg];
    const unsigned short* sb = (const unsigned short*)a.src[seg];
    unsigned short* d = (unsigned short*)a.dst[seg];
    for (int i = (blockIdx.x * 256 + threadIdx.x) * 4; i < n; i += gridDim.x * 1024) {
        ushort4 o;
        if (inf32) {
            float4 v = *(const float4*)(sf + i);
            o.x = f2b(v.x); o.y = f2b(v.y); o.z = f2b(v.z); o.w = f2b(v.w);
        } else {
            o = *(const ushort4*)(sb + i);
        }
        *(ushort4*)(d + i) = o;
    }
}

__global__ __launch_bounds__(256) void cvt_to_f32_k(const int* __restrict__ flag, CvtArgs11 a)
{
    const int seg = blockIdx.y, n = a.n[seg];
    const bool inf32 = (*flag != 0);
    const float* sf = (const float*)a.src[seg];
    const unsigned short* sb = (const unsigned short*)a.src[seg];
    float* d = (float*)a.dst[seg];
    for (int i = (blockIdx.x * 256 + threadIdx.x) * 4; i < n; i += gridDim.x * 1024) {
        float4 o;
        if (inf32) {
            o = *(const float4*)(sf + i);
        } else {
            ushort4 v = *(const ushort4*)(sb + i);
            o.x = b2f(v.x); o.y = b2f(v.y); o.z = b2f(v.z); o.w = b2f(v.w);
        }
        *(float4*)(d + i) = o;
    }
}

// ---------------- LayerNorm: one wave per token (H=256, 4 f32/lane) ---------------
__global__ __launch_bounds__(256) void ln_kernel(
    const float* __restrict__ x, const float* __restrict__ w,
    const float* __restrict__ b, unsigned short* __restrict__ out)
{
    const int wave = threadIdx.x >> 6, lane = threadIdx.x & 63;
    const int token = blockIdx.x * 4 + wave;
    const int c = lane * 4;
    const size_t rowo = (size_t)token * CH + c;
    float4 u = *(const float4*)(x + rowo);
    float v0 = u.x, v1 = u.y, v2 = u.z, v3 = u.w;
    float s = v0 + v1 + v2 + v3;
    float q = v0*v0 + v1*v1 + v2*v2 + v3*v3;
    #pragma unroll
    for (int m = 1; m < 64; m <<= 1) { s += __shfl_xor(s, m, 64); q += __shfl_xor(q, m, 64); }
    float mean = s * (1.0f/256.0f);
    float var  = q * (1.0f/256.0f) - mean*mean;
    float inv  = rsqrtf(var + 1e-12f);
    float4 ww = *(const float4*)(w + c);
    float4 bb = *(const float4*)(b + c);
    ushort4 o;
    o.x = f2b(ww.x * (v0-mean)*inv + bb.x);
    o.y = f2b(ww.y * (v1-mean)*inv + bb.y);
    o.z = f2b(ww.z * (v2-mean)*inv + bb.z);
    o.w = f2b(ww.w * (v3-mean)*inv + bb.w);
    *(ushort4*)(out + rowo) = o;
}

// ---------------- Generic 128x128 bf16 MFMA GEMM: C = act((A@W^T + b)*osc) --------
template<bool GELU, bool RESID, bool HEADSTORE, bool OUTF32, bool OUTDYN>
__device__ __forceinline__ void gemm_core(
    const unsigned short* __restrict__ A, const unsigned short* __restrict__ W,
    const float* __restrict__ bias, const float* __restrict__ resid,
    void* __restrict__ out, const int* __restrict__ flag,
    int K, int N, int m0, int n0, float oscale)
{
    __shared__ __align__(16) unsigned short lA[128*32];
    __shared__ __align__(16) unsigned short lB[128*32];
    const int tid  = threadIdx.x;
    const int lane = tid & 63;
    const int wave = tid >> 6;
    const int wr = (wave >> 1) * 64;
    const int wc = (wave & 1) * 64;
    const int g = lane >> 4, r16 = lane & 15;
    const int lrow = lane >> 2;        // 0..15 rows within 1KB chunk
    const int lch  = lane & 3;         // 16B chunk within 64B row

    const f32x4 zero = {0.f, 0.f, 0.f, 0.f};
    f32x4 acc[4][4];
    #pragma unroll
    for (int m = 0; m < 4; ++m)
        #pragma unroll
        for (int n = 0; n < 4; ++n) acc[m][n] = zero;

    for (int k0 = 0; k0 < K; k0 += 32) {
        #pragma unroll
        for (int i = 0; i < 2; ++i) {
            int chunk = wave + i * 4;              // 0..7 (1KB chunks of 8KB tile)
            int row = chunk * 16 + lrow;           // tile row
            const unsigned short* ga = A + (size_t)(m0 + row) * K + k0 + lch * 8;
            GLOAD_LDS16(ga, &lA[chunk * 512]);
            const unsigned short* gw = W + (size_t)(n0 + row) * K + k0 + lch * 8;
            GLOAD_LDS16(gw, &lB[chunk * 512]);
        }
        __syncthreads();
        bf16x8 af[4], wf[4];
        #pragma unroll
        for (int m = 0; m < 4; ++m) af[m] = *(const bf16x8*)&lA[(wr + m*16 + r16) * 32 + g * 8];
        #pragma unroll
        for (int n = 0; n < 4; ++n) wf[n] = *(const bf16x8*)&lB[(wc + n*16 + r16) * 32 + g * 8];
        #pragma unroll
        for (int m = 0; m < 4; ++m)
            #pragma unroll
            for (int n = 0; n < 4; ++n)
                acc[m][n] = mfma16(af[m], wf[n], acc[m][n]);
        __syncthreads();
    }

    const bool of32dyn = OUTDYN ? (*flag != 0) : false;
    #pragma unroll
    for (int n = 0; n < 4; ++n) {
        int col = n0 + wc + n*16 + r16;
        float bv = bias[col];
        #pragma unroll
        for (int m = 0; m < 4; ++m) {
            int row0 = m0 + wr + m*16 + g*4;
            #pragma unroll
            for (int r = 0; r < 4; ++r) {
                int row = row0 + r;
                float v = (acc[m][n][r] + bv) * oscale;
                if (GELU) {
                    float a = 0.79788456080286541f * (v + 0.044715f * v * v * v);
                    v = v * (1.0f / (1.0f + __expf(-2.0f * a)));   // 0.5v(1+tanh(a))
                }
                if (RESID) v += resid[(size_t)row * N + col];
                size_t oidx;
                if (HEADSTORE) {
                    int hh = col >> 6, d = col & 63;
                    int bb = row >> 11, ss = row & 2047;
                    oidx = ((((size_t)bb * CNH + hh) * CS) + ss) * CDH + d;
                } else {
                    oidx = (size_t)row * N + col;
                }
                if (OUTF32)      ((float*)out)[oidx] = v;
                else if (OUTDYN) {
                    if (of32dyn) ((float*)out)[oidx] = v;
                    else         ((unsigned short*)out)[oidx] = f2b(v);
                }
                else             ((unsigned short*)out)[oidx] = f2b(v);
            }
        }
    }
}

__global__ __launch_bounds__(256) void k_qkv(
    const unsigned short* __restrict__ xhat,
    const unsigned short* Wq, const float* bq, unsigned short* q,
    const unsigned short* Wk, const float* bk, unsigned short* k,
    const unsigned short* Wv, const float* bv, unsigned short* v)
{
    const unsigned short* W  = blockIdx.z == 0 ? Wq : (blockIdx.z == 1 ? Wk : Wv);
    const float*          bi = blockIdx.z == 0 ? bq : (blockIdx.z == 1 ? bk : bv);
    unsigned short*       o  = blockIdx.z == 0 ? q  : (blockIdx.z == 1 ? k  : v);
    const float osc = blockIdx.z == 0 ? QSCALE : 1.0f;     // fold log2e/sqrt(DH) into Q
    gemm_core<false, false, true, false, false>(xhat, W, bi, nullptr, o, nullptr,
                                                CH, CH, blockIdx.x * 128, blockIdx.y * 128, osc);
}

__global__ __launch_bounds__(256) void k_oproj(
    const unsigned short* __restrict__ A, const unsigned short* __restrict__ W,
    const float* __restrict__ bias, const float* __restrict__ resid,
    float* __restrict__ out)
{
    gemm_core<false, true, false, true, false>(A, W, bias, resid, out, nullptr,
                                               CH, CH, blockIdx.x * 128, blockIdx.y * 128, 1.0f);
}

__global__ __launch_bounds__(256) void k_ffn1(
    const unsigned short* __restrict__ A, const unsigned short* __restrict__ W,
    const float* __restrict__ bias, unsigned short* __restrict__ out)
{
    gemm_core<true, false, false, false, false>(A, W, bias, nullptr, out, nullptr,
                                                CH, 4*CH, blockIdx.x * 128, blockIdx.y * 128, 1.0f);
}

__global__ __launch_bounds__(256) void k_ffn2(
    const unsigned short* __restrict__ A, const unsigned short* __restrict__ W,
    const float* __restrict__ bias, const float* __restrict__ resid,
    void* __restrict__ out, const int* __restrict__ flag)
{
    gemm_core<false, true, false, false, true>(A, W, bias, resid, out, flag,
                                               4*CH, CH, blockIdx.x * 128, blockIdx.y * 128, 1.0f);
}

// ---------------- V transpose: [bh][S][DH] -> [bh][DH][S] -------------------------
__global__ __launch_bounds__(256) void vtrans_kernel(
    const unsigned short* __restrict__ v, unsigned short* __restrict__ vt)
{
    __shared__ unsigned short T[64 * 72];
    const int bh = blockIdx.y, s0 = blockIdx.x * 64, tid = threadIdx.x;
    const size_t ibase = (size_t)bh * CS * CDH;
    const size_t obase = (size_t)bh * CDH * CS;
    #pragma unroll
    for (int i = 0; i < 2; ++i) {
        int t2 = tid + i * 256;
        int row = t2 >> 3, ch = t2 & 7;          // row: s-local, ch: d-chunk
        uint4 dv = *(const uint4*)(v + ibase + (size_t)(s0 + row) * CDH + ch * 8);
        *(uint4*)&T[row * 72 + ch * 8] = dv;
    }
    __syncthreads();
    #pragma unroll
    for (int i = 0; i < 2; ++i) {
        int t2 = tid + i * 256;
        int d = t2 >> 3, ch = t2 & 7;            // d: out row, ch: s-chunk
        unsigned short tmp[8];
        #pragma unroll
        for (int j = 0; j < 8; ++j) tmp[j] = T[(ch * 8 + j) * 72 + d];
        *(uint4*)(vt + obase + (size_t)d * CS + s0 + ch * 8) = *(uint4*)tmp;
    }
}

// ---------------- Flash attention, no-max-subtract softmax ------------------------
// 512 thr / 8 waves x 16 q-rows; QBLK=128, KVBLK=128. Q pre-scaled by log2e/8 and
// masked rows pre-zeroed => p = exp2(s) with NO max/rescale/shuffle in hot loop.
// LDS XOR-swizzle: byte ^= ((row&7)<<4). l accumulated per-lane, reduced once.
__global__ __launch_bounds__(512, 4) void attn_kernel(
    const unsigned short* __restrict__ Q, const unsigned short* __restrict__ Kp,
    const unsigned short* __restrict__ Vt, const int* __restrict__ mask,
    unsigned short* __restrict__ out)
{
    __shared__ __align__(16) unsigned short Qs[128 * 64];   // [q][d]  128B rows
    __shared__ __align__(16) unsigned short Ks[128 * 64];   // [k][d]  128B rows
    __shared__ __align__(16) unsigned short Vs[64 * 128];   // [d][k]  256B rows
    __shared__ __align__(16) unsigned short Ps[128 * 128];  // [q][k]  256B rows

    const int tid = threadIdx.x, lane = tid & 63, wave = tid >> 6;
    const int bh = blockIdx.y, bb = bh >> 2, hh = bh & 3;
    const int q0 = blockIdx.x * 128;
    const size_t baseQ = (size_t)bh * CS * CDH;   // Q,K: [S][DH]
    const size_t baseT = (size_t)bh * CDH * CS;   // Vt:  [DH][S]

    const int g = lane >> 4, r16 = lane & 15;
    const int wq = wave * 16;
    const int swz = (r16 & 7) << 4;               // frag-read swizzle (row%8 == r16%8)

    // ---- Q staging (mask folded in: masked q-rows zeroed => uniform softmax) ----
    #pragma unroll
    for (int i = 0; i < 2; ++i) {
        int t2 = tid + i * 512;
        int row = t2 >> 3, ch = t2 & 7;
        uint4 dv = *(const uint4*)(Q + baseQ + (size_t)(q0 + row) * CDH + ch * 8);
        if (mask[bb * CS + q0 + row] == 0) { dv.x = 0; dv.y = 0; dv.z = 0; dv.w = 0; }
        *(uint4*)((char*)Qs + row * 128 + ((ch * 16) ^ ((row & 7) << 4))) = dv;
    }

    f32x4 o_acc[4];
    float psum[4];
    #pragma unroll
    for (int n = 0; n < 4; ++n) o_acc[n] = (f32x4){0.f, 0.f, 0.f, 0.f};
    #pragma unroll
    for (int r = 0; r < 4; ++r) psum[r] = 0.f;

    // staging geometry (1024 16B tasks each for K and V; 2 per thread)
    const int kr0 = tid >> 3,  kc0 = tid & 7;          // K task A: rows 0..63
    const int kr1 = kr0 + 64;                          // K task B: rows 64..127
    const int vd0 = tid >> 4,  vc0 = tid & 15;         // V task A: d 0..31
    const int vd1 = vd0 + 32;                          // V task B: d 32..63
    char* kdstA = (char*)Ks + kr0 * 128 + ((kc0 * 16) ^ ((kr0 & 7) << 4));
    char* kdstB = (char*)Ks + kr1 * 128 + ((kc0 * 16) ^ ((kr1 & 7) << 4));
    char* vdstA = (char*)Vs + vd0 * 256 + ((vc0 * 16) ^ ((vd0 & 7) << 4));
    char* vdstB = (char*)Vs + vd1 * 256 + ((vc0 * 16) ^ ((vd1 & 7) << 4));

    uint4 kva, kvb, vva, vvb;
    kva = *(const uint4*)(Kp + baseQ + (size_t)kr0 * CDH + kc0 * 8);
    kvb = *(const uint4*)(Kp + baseQ + (size_t)kr1 * CDH + kc0 * 8);
    vva = *(const uint4*)(Vt + baseT + (size_t)vd0 * CS + vc0 * 8);
    vvb = *(const uint4*)(Vt + baseT + (size_t)vd1 * CS + vc0 * 8);

    for (int kt = 0; kt < CS; kt += 128) {
        *(uint4*)kdstA = kva;  *(uint4*)kdstB = kvb;
        *(uint4*)vdstA = vva;  *(uint4*)vdstB = vvb;
        __syncthreads();
        if (kt + 128 < CS) {                           // prefetch next tile
            kva = *(const uint4*)(Kp + baseQ + (size_t)(kt + 128 + kr0) * CDH + kc0 * 8);
            kvb = *(const uint4*)(Kp + baseQ + (size_t)(kt + 128 + kr1) * CDH + kc0 * 8);
            vva = *(const uint4*)(Vt + baseT + (size_t)vd0 * CS + (kt + 128) + vc0 * 8);
            vvb = *(const uint4*)(Vt + baseT + (size_t)vd1 * CS + (kt + 128) + vc0 * 8);
        }

        // ---- QK^T: S[wq+g*4+r][n*16+r16] ----
        f32x4 s_acc[8];
        #pragma unroll
        for (int n = 0; n < 8; ++n) s_acc[n] = (f32x4){0.f, 0.f, 0.f, 0.f};
        __builtin_amdgcn_s_setprio(1);
        #pragma unroll
        for (int kk = 0; kk < 2; ++kk) {
            bf16x8 aq = *(const bf16x8*)((char*)Qs + (wq + r16) * 128 + ((kk*64 + g*16) ^ swz));
            #pragma unroll
            for (int n = 0; n < 8; ++n) {
                bf16x8 bk2 = *(const bf16x8*)((char*)Ks + (n*16 + r16) * 128 + ((kk*64 + g*16) ^ swz));
                s_acc[n] = mfma16(aq, bk2, s_acc[n]);
            }
        }
        __builtin_amdgcn_s_setprio(0);

        // ---- softmax numerator: p = exp2(s); per-lane partial row-sum ----
        #pragma unroll
        for (int r = 0; r < 4; ++r) {
            const int rloc = wq + g * 4 + r;
            char* prow = (char*)Ps + rloc * 256;
            const int pswz = (rloc & 7) << 4;
            float acc = 0.f;
            #pragma unroll
            for (int n = 0; n < 8; ++n) {
                float p = fexp2(s_acc[n][r]);
                acc += p;
                *(unsigned short*)(prow + (((n*16 + r16) * 2) ^ pswz)) = f2b_fast(p);
            }
            psum[r] += acc;
        }
        // no barrier: Ps rows are wave-exclusive; wave LDS ops are in-order

        // ---- O += P @ V ----
        __builtin_amdgcn_s_setprio(1);
        #pragma unroll
        for (int kk = 0; kk < 4; ++kk) {
            bf16x8 ap = *(const bf16x8*)((char*)Ps + (wq + r16) * 256 + ((kk*64 + g*16) ^ swz));
            #pragma unroll
            for (int n = 0; n < 4; ++n) {
                bf16x8 bv2 = *(const bf16x8*)((char*)Vs + (n*16 + r16) * 256 + ((kk*64 + g*16) ^ swz));
                o_acc[n] = mfma16(ap, bv2, o_acc[n]);
            }
        }
        __builtin_amdgcn_s_setprio(0);
        __syncthreads();                               // protect Ks/Vs before restage
    }

    #pragma unroll
    for (int r = 0; r < 4; ++r) {
        float l = psum[r];
        #pragma unroll
        for (int d = 1; d < 16; d <<= 1) l += __shfl_xor(l, d, 64);
        float inv = 1.0f / l;
        const int rloc = wq + g * 4 + r;
        #pragma unroll
        for (int n = 0; n < 4; ++n)
            out[((size_t)(bb * CS + q0 + rloc)) * CH + hh * CDH + n*16 + r16] =
                f2b(o_acc[n][r] * inv);
    }
}

// ----------------------------------------------------------------------------------
extern "C" void kernel_launch(void* const* d_in, const int* in_sizes, int n_in,
                              void* d_out, int out_size, void* d_ws, size_t ws_size,
                              hipStream_t stream)
{
    const void* hidden = d_in[0];
    const void* Wq = d_in[1];  const void* bq = d_in[2];
    const void* Wk = d_in[3];  const void* bk = d_in[4];
    const void* Wv = d_in[5];  const void* bv = d_in[6];
    const void* Wo = d_in[7];  const void* bo = d_in[8];
    const void* W1 = d_in[9];  const void* b1 = d_in[10];
    const void* W2 = d_in[11]; const void* b2 = d_in[12];
    const void* ln1w = d_in[13]; const void* ln1b = d_in[14];
    const void* ln2w = d_in[15]; const void* ln2b = d_in[16];
    const int* mask = (const int*)d_in[17];

    char* ws = (char*)d_ws;
    const size_t KB = 1u << 10, MB = 1u << 20;
    int*            flag  = (int*)ws;
    float*          bqf   = (float*)(ws + 4*KB);
    float*          bkf   = (float*)(ws + 8*KB);
    float*          bvf   = (float*)(ws + 12*KB);
    float*          bof   = (float*)(ws + 16*KB);
    float*          b1f   = (float*)(ws + 20*KB);
    float*          b2f_  = (float*)(ws + 28*KB);
    float*          ln1wf = (float*)(ws + 32*KB);
    float*          ln1bf = (float*)(ws + 36*KB);
    float*          ln2wf = (float*)(ws + 40*KB);
    float*          ln2bf = (float*)(ws + 44*KB);
    unsigned short* Wqb   = (unsigned short*)(ws + 1*MB);
    unsigned short* Wkb   = (unsigned short*)(ws + 1*MB + 256*KB);
    unsigned short* Wvb   = (unsigned short*)(ws + 1*MB + 512*KB);
    unsigned short* Wob   = (unsigned short*)(ws + 1*MB + 768*KB);
    unsigned short* W1b   = (unsigned short*)(ws + 2*MB);
    unsigned short* W2b   = (unsigned short*)(ws + 2*MB + 512*KB);
    float*          hf32  = (float*)(ws + 3*MB);            // [T][H] f32, 16MB
    unsigned short* xhat  = (unsigned short*)(ws + 19*MB);  // 8MB
    unsigned short* qb    = (unsigned short*)(ws + 27*MB);  // 8MB
    unsigned short* kb    = (unsigned short*)(ws + 35*MB);  // 8MB
    unsigned short* vb    = (unsigned short*)(ws + 43*MB);  // 8MB
    unsigned short* attnb = xhat;                           // xhat dead after QKV
    float*          hid2f = (float*)(ws + 35*MB);           // 16MB over kb+vb (dead)
    unsigned short* vtb   = (unsigned short*)(ws + 51*MB);  // 8MB (pre-FFN lifetime)
    unsigned short* yhat  = qb;                             // qb dead after attn
    unsigned short* h1g   = (unsigned short*)(ws + 51*MB);  // [T][1024] bf16, 32MB

    dim3 blk(256);
    detect_kernel<<<1, blk, 0, stream>>>((const unsigned short*)hidden, flag);

    CvtArgs6 cw;
    cw.src[0]=Wq;  cw.dst[0]=Wqb; cw.n[0]=CH*CH;
    cw.src[1]=Wk;  cw.dst[1]=Wkb; cw.n[1]=CH*CH;
    cw.src[2]=Wv;  cw.dst[2]=Wvb; cw.n[2]=CH*CH;
    cw.src[3]=Wo;  cw.dst[3]=Wob; cw.n[3]=CH*CH;
    cw.src[4]=W1;  cw.dst[4]=W1b; cw.n[4]=4*CH*CH;
    cw.src[5]=W2;  cw.dst[5]=W2b; cw.n[5]=4*CH*CH;
    cvt_to_bf16_k<<<dim3(64, 6), blk, 0, stream>>>(flag, cw);

    CvtArgs11 cf;
    cf.src[0]=hidden; cf.dst[0]=hf32;  cf.n[0]=CT*CH;
    cf.src[1]=bq;     cf.dst[1]=bqf;   cf.n[1]=CH;
    cf.src[2]=bk;     cf.dst[2]=bkf;   cf.n[2]=CH;
    cf.src[3]=bv;     cf.dst[3]=bvf;   cf.n[3]=CH;
    cf.src[4]=bo;     cf.dst[4]=bof;   cf.n[4]=CH;
    cf.src[5]=b1;     cf.dst[5]=b1f;   cf.n[5]=4*CH;
    cf.src[6]=b2;     cf.dst[6]=b2f_;  cf.n[6]=CH;
    cf.src[7]=ln1w;   cf.dst[7]=ln1wf; cf.n[7]=CH;
    cf.src[8]=ln1b;   cf.dst[8]=ln1bf; cf.n[8]=CH;
    cf.src[9]=ln2w;   cf.dst[9]=ln2wf; cf.n[9]=CH;
    cf.src[10]=ln2b;  cf.dst[10]=ln2bf;cf.n[10]=CH;
    cvt_to_f32_k<<<dim3(512, 11), blk, 0, stream>>>(flag, cf);

    ln_kernel<<<CT / 4, blk, 0, stream>>>(hf32, ln1wf, ln1bf, xhat);
    k_qkv<<<dim3(CT / 128, CH / 128, 3), blk, 0, stream>>>(xhat, Wqb, bqf, qb,
                                                           Wkb, bkf, kb, Wvb, bvf, vb);
    vtrans_kernel<<<dim3(CS / 64, CB * CNH), blk, 0, stream>>>(vb, vtb);
    attn_kernel<<<dim3(CS / 128, CB * CNH), dim3(512), 0, stream>>>(qb, kb, vtb, mask, attnb);
    k_oproj<<<dim3(CT / 128, CH / 128), blk, 0, stream>>>(attnb, Wob, bof, hf32, hid2f);
    ln_kernel<<<CT / 4, blk, 0, stream>>>(hid2f, ln2wf, ln2bf, yhat);
    k_ffn1<<<dim3(CT / 128, (4 * CH) / 128), blk, 0, stream>>>(yhat, W1b, b1f, h1g);
    k_ffn2<<<dim3(CT / 128, CH / 128), blk, 0, stream>>>(h1g, W2b, b2f_, hid2f,
                                                         d_out, flag);
}

// Round 5
// 167.810 us; speedup vs baseline: 1.4970x; 1.0323x over previous
//
#include <hip/hip_runtime.h>
#include <hip/hip_bf16.h>
#include <cstdint>
#include <cstddef>

constexpr int CB  = 8;
constexpr int CS  = 2048;
constexpr int CH  = 256;
constexpr int CNH = 4;
constexpr int CDH = 64;
constexpr int CT  = CB * CS;   // 16384 tokens

typedef __attribute__((ext_vector_type(8)))  __bf16 bf16x8;
typedef __attribute__((ext_vector_type(4)))  float  f32x4;
typedef __attribute__((ext_vector_type(16))) float  f32x16;
typedef __attribute__((ext_vector_type(2)))  int    i32x2;

__device__ __forceinline__ float b2f(unsigned short u) {
    union { float f; unsigned int i; } v; v.i = ((unsigned int)u) << 16; return v.f;
}
__device__ __forceinline__ unsigned short f2b(float f) {
    union { float f; unsigned int i; } v; v.f = f;
    unsigned int r = v.i + 0x7FFFu + ((v.i >> 16) & 1u);
    return (unsigned short)(r >> 16);
}
__device__ __forceinline__ unsigned short f2b_fast(float f) {  // round-half-up
    union { float f; unsigned int i; } v; v.f = f;
    return (unsigned short)((v.i + 0x8000u) >> 16);
}
__device__ __forceinline__ unsigned int packbf(float a, float b) {
    return (unsigned int)f2b_fast(a) | ((unsigned int)f2b_fast(b) << 16);
}
__device__ __forceinline__ float fexp2(float x) {
#if __has_builtin(__builtin_amdgcn_exp2f)
    return __builtin_amdgcn_exp2f(x);
#else
    float r; asm("v_exp_f32 %0, %1" : "=v"(r) : "v"(x)); return r;
#endif
}
__device__ __forceinline__ f32x4 mfma16(bf16x8 a, bf16x8 b, f32x4 c) {
    return __builtin_amdgcn_mfma_f32_16x16x32_bf16(a, b, c, 0, 0, 0);
}
__device__ __forceinline__ f32x16 mfma32(bf16x8 a, bf16x8 b, f32x16 c) {
    return __builtin_amdgcn_mfma_f32_32x32x16_bf16(a, b, c, 0, 0, 0);
}
__device__ __forceinline__ f32x16 zero16() {
    f32x16 z;
    #pragma unroll
    for (int i = 0; i < 16; ++i) z[i] = 0.f;
    return z;
}

#define GLOAD_LDS16(gptr, lptr)                                                        \
    __builtin_amdgcn_global_load_lds((const __attribute__((address_space(1))) void*)(gptr), \
                                     (__attribute__((address_space(3))) void*)(lptr), 16, 0, 0)

// log2(e)/sqrt(DH): folded into Q projection so softmax uses raw exp2
#define QSCALE 0.1803368801111204f

// ---------------- dtype detect: reading f32 data as bf16 yields huge/NaN values ----
__global__ __launch_bounds__(256) void detect_kernel(
    const unsigned short* __restrict__ h, int* __restrict__ flag)
{
    __shared__ int s_bad;
    const int tid = threadIdx.x;
    if (tid == 0) s_bad = 0;
    __syncthreads();
    bool bad = false;
    for (int i = tid; i < 2048; i += 256) {
        float v = b2f(h[i]);
        if (!(fabsf(v) < 1e25f)) bad = true;   // NaN also lands here
    }
    if (bad) s_bad = 1;
    __syncthreads();
    if (tid == 0) *flag = s_bad;               // 1 => buffers are f32, 0 => bf16
}

// ---------------- converters (runtime input dtype via flag) -----------------------
struct CvtArgs6  { const void* src[6];  void* dst[6];  int n[6]; };
struct CvtArgs11 { const void* src[11]; void* dst[11]; int n[11]; };

__global__ __launch_bounds__(256) void cvt_to_bf16_k(const int* __restrict__ flag, CvtArgs6 a)
{
    const int seg = blockIdx.y, n = a.n[seg];
    const bool inf32 = (*flag != 0);
    const float* sf = (const float*)a.src[seg];
    const unsigned short* sb = (const unsigned short*)a.src[seg];
    unsigned short* d = (unsigned short*)a.dst[seg];
    for (int i = (blockIdx.x * 256 + threadIdx.x) * 4; i < n; i += gridDim.x * 1024) {
        ushort4 o;
        if (inf32) {
            float4 v = *(const float4*)(sf + i);
            o.x = f2b(v.x); o.y = f2b(v.y); o.z = f2b(v.z); o.w = f2b(v.w);
        } else {
            o = *(const ushort4*)(sb + i);
        }
        *(ushort4*)(d + i) = o;
    }
}

__global__ __launch_bounds__(256) void cvt_to_f32_k(const int* __restrict__ flag, CvtArgs11 a)
{
    const int seg = blockIdx.y, n = a.n[seg];
    const bool inf32 = (*flag != 0);
    const float* sf = (const float*)a.src[seg];
    const unsigned short* sb = (const unsigned short*)a.src[seg];
    float* d = (float*)a.dst[seg];
    for (int i = (blockIdx.x * 256 + threadIdx.x) * 4; i < n; i += gridDim.x * 1024) {
        float4 o;
        if (inf32) {
            o = *(const float4*)(sf + i);
        } else {
            ushort4 v = *(const ushort4*)(sb + i);
            o.x = b2f(v.x); o.y = b2f(v.y); o.z = b2f(v.z); o.w = b2f(v.w);
        }
        *(float4*)(d + i) = o;
    }
}

// ---------------- LayerNorm: one wave per token (H=256, 4 f32/lane) ---------------
__global__ __launch_bounds__(256) void ln_kernel(
    const float* __restrict__ x, const float* __restrict__ w,
    const float* __restrict__ b, unsigned short* __restrict__ out)
{
    const int wave = threadIdx.x >> 6, lane = threadIdx.x & 63;
    const int token = blockIdx.x * 4 + wave;
    const int c = lane * 4;
    const size_t rowo = (size_t)token * CH + c;
    float4 u = *(const float4*)(x + rowo);
    float v0 = u.x, v1 = u.y, v2 = u.z, v3 = u.w;
    float s = v0 + v1 + v2 + v3;
    float q = v0*v0 + v1*v1 + v2*v2 + v3*v3;
    #pragma unroll
    for (int m = 1; m < 64; m <<= 1) { s += __shfl_xor(s, m, 64); q += __shfl_xor(q, m, 64); }
    float mean = s * (1.0f/256.0f);
    float var  = q * (1.0f/256.0f) - mean*mean;
    float inv  = rsqrtf(var + 1e-12f);
    float4 ww = *(const float4*)(w + c);
    float4 bb = *(const float4*)(b + c);
    ushort4 o;
    o.x = f2b(ww.x * (v0-mean)*inv + bb.x);
    o.y = f2b(ww.y * (v1-mean)*inv + bb.y);
    o.z = f2b(ww.z * (v2-mean)*inv + bb.z);
    o.w = f2b(ww.w * (v3-mean)*inv + bb.w);
    *(ushort4*)(out + rowo) = o;
}

// ---------------- Generic 128x128 bf16 MFMA GEMM: C = act((A@W^T + b)*osc) --------
template<bool GELU, bool RESID, bool HEADSTORE, bool OUTF32, bool OUTDYN>
__device__ __forceinline__ void gemm_core(
    const unsigned short* __restrict__ A, const unsigned short* __restrict__ W,
    const float* __restrict__ bias, const float* __restrict__ resid,
    void* __restrict__ out, const int* __restrict__ flag,
    int K, int N, int m0, int n0, float oscale)
{
    __shared__ __align__(16) unsigned short lA[128*32];
    __shared__ __align__(16) unsigned short lB[128*32];
    const int tid  = threadIdx.x;
    const int lane = tid & 63;
    const int wave = tid >> 6;
    const int wr = (wave >> 1) * 64;
    const int wc = (wave & 1) * 64;
    const int g = lane >> 4, r16 = lane & 15;
    const int lrow = lane >> 2;        // 0..15 rows within 1KB chunk
    const int lch  = lane & 3;         // 16B chunk within 64B row

    const f32x4 zero = {0.f, 0.f, 0.f, 0.f};
    f32x4 acc[4][4];
    #pragma unroll
    for (int m = 0; m < 4; ++m)
        #pragma unroll
        for (int n = 0; n < 4; ++n) acc[m][n] = zero;

    for (int k0 = 0; k0 < K; k0 += 32) {
        #pragma unroll
        for (int i = 0; i < 2; ++i) {
            int chunk = wave + i * 4;              // 0..7 (1KB chunks of 8KB tile)
            int row = chunk * 16 + lrow;           // tile row
            const unsigned short* ga = A + (size_t)(m0 + row) * K + k0 + lch * 8;
            GLOAD_LDS16(ga, &lA[chunk * 512]);
            const unsigned short* gw = W + (size_t)(n0 + row) * K + k0 + lch * 8;
            GLOAD_LDS16(gw, &lB[chunk * 512]);
        }
        __syncthreads();
        bf16x8 af[4], wf[4];
        #pragma unroll
        for (int m = 0; m < 4; ++m) af[m] = *(const bf16x8*)&lA[(wr + m*16 + r16) * 32 + g * 8];
        #pragma unroll
        for (int n = 0; n < 4; ++n) wf[n] = *(const bf16x8*)&lB[(wc + n*16 + r16) * 32 + g * 8];
        #pragma unroll
        for (int m = 0; m < 4; ++m)
            #pragma unroll
            for (int n = 0; n < 4; ++n)
                acc[m][n] = mfma16(af[m], wf[n], acc[m][n]);
        __syncthreads();
    }

    const bool of32dyn = OUTDYN ? (*flag != 0) : false;
    #pragma unroll
    for (int n = 0; n < 4; ++n) {
        int col = n0 + wc + n*16 + r16;
        float bv = bias[col];
        #pragma unroll
        for (int m = 0; m < 4; ++m) {
            int row0 = m0 + wr + m*16 + g*4;
            #pragma unroll
            for (int r = 0; r < 4; ++r) {
                int row = row0 + r;
                float v = (acc[m][n][r] + bv) * oscale;
                if (GELU) {
                    float a = 0.79788456080286541f * (v + 0.044715f * v * v * v);
                    v = v * (1.0f / (1.0f + __expf(-2.0f * a)));   // 0.5v(1+tanh(a))
                }
                if (RESID) v += resid[(size_t)row * N + col];
                size_t oidx;
                if (HEADSTORE) {
                    int hh = col >> 6, d = col & 63;
                    int bb = row >> 11, ss = row & 2047;
                    oidx = ((((size_t)bb * CNH + hh) * CS) + ss) * CDH + d;
                } else {
                    oidx = (size_t)row * N + col;
                }
                if (OUTF32)      ((float*)out)[oidx] = v;
                else if (OUTDYN) {
                    if (of32dyn) ((float*)out)[oidx] = v;
                    else         ((unsigned short*)out)[oidx] = f2b(v);
                }
                else             ((unsigned short*)out)[oidx] = f2b(v);
            }
        }
    }
}

__global__ __launch_bounds__(256) void k_qkv(
    const unsigned short* __restrict__ xhat,
    const unsigned short* Wq, const float* bq, unsigned short* q,
    const unsigned short* Wk, const float* bk, unsigned short* k,
    const unsigned short* Wv, const float* bv, unsigned short* v)
{
    const unsigned short* W  = blockIdx.z == 0 ? Wq : (blockIdx.z == 1 ? Wk : Wv);
    const float*          bi = blockIdx.z == 0 ? bq : (blockIdx.z == 1 ? bk : bv);
    unsigned short*       o  = blockIdx.z == 0 ? q  : (blockIdx.z == 1 ? k  : v);
    const float osc = blockIdx.z == 0 ? QSCALE : 1.0f;     // fold log2e/sqrt(DH) into Q
    gemm_core<false, false, true, false, false>(xhat, W, bi, nullptr, o, nullptr,
                                                CH, CH, blockIdx.x * 128, blockIdx.y * 128, osc);
}

__global__ __launch_bounds__(256) void k_oproj(
    const unsigned short* __restrict__ A, const unsigned short* __restrict__ W,
    const float* __restrict__ bias, const float* __restrict__ resid,
    float* __restrict__ out)
{
    gemm_core<false, true, false, true, false>(A, W, bias, resid, out, nullptr,
                                               CH, CH, blockIdx.x * 128, blockIdx.y * 128, 1.0f);
}

__global__ __launch_bounds__(256) void k_ffn1(
    const unsigned short* __restrict__ A, const unsigned short* __restrict__ W,
    const float* __restrict__ bias, unsigned short* __restrict__ out)
{
    gemm_core<true, false, false, false, false>(A, W, bias, nullptr, out, nullptr,
                                                CH, 4*CH, blockIdx.x * 128, blockIdx.y * 128, 1.0f);
}

__global__ __launch_bounds__(256) void k_ffn2(
    const unsigned short* __restrict__ A, const unsigned short* __restrict__ W,
    const float* __restrict__ bias, const float* __restrict__ resid,
    void* __restrict__ out, const int* __restrict__ flag)
{
    gemm_core<false, true, false, false, true>(A, W, bias, resid, out, flag,
                                               4*CH, CH, blockIdx.x * 128, blockIdx.y * 128, 1.0f);
}

// ---------------- V transpose: [bh][S][DH] -> [bh][DH][S] -------------------------
__global__ __launch_bounds__(256) void vtrans_kernel(
    const unsigned short* __restrict__ v, unsigned short* __restrict__ vt)
{
    __shared__ unsigned short T[64 * 72];
    const int bh = blockIdx.y, s0 = blockIdx.x * 64, tid = threadIdx.x;
    const size_t ibase = (size_t)bh * CS * CDH;
    const size_t obase = (size_t)bh * CDH * CS;
    #pragma unroll
    for (int i = 0; i < 2; ++i) {
        int t2 = tid + i * 256;
        int row = t2 >> 3, ch = t2 & 7;          // row: s-local, ch: d-chunk
        uint4 dv = *(const uint4*)(v + ibase + (size_t)(s0 + row) * CDH + ch * 8);
        *(uint4*)&T[row * 72 + ch * 8] = dv;
    }
    __syncthreads();
    #pragma unroll
    for (int i = 0; i < 2; ++i) {
        int t2 = tid + i * 256;
        int d = t2 >> 3, ch = t2 & 7;            // d: out row, ch: s-chunk
        unsigned short tmp[8];
        #pragma unroll
        for (int j = 0; j < 8; ++j) tmp[j] = T[(ch * 8 + j) * 72 + d];
        *(uint4*)(vt + obase + (size_t)d * CS + s0 + ch * 8) = *(uint4*)tmp;
    }
}

// ---------------- Flash attention, 32x32 MFMA, in-register P ----------------------
// 512 thr / 8 waves = 4 q-blocks(32) x 2 k-halves(64). QBLK=128, KVBLK=128.
// Swapped QK^T (mfma(K,Q)) puts P in registers per q-col; pack+permlane32_swap
// builds PV A-fragments with ZERO P LDS traffic. K/V staged via global_load_lds
// into chunked layouts (conflict-free b128 reads), double-buffered.
__global__ __launch_bounds__(512, 4) void attn_kernel(
    const unsigned short* __restrict__ Q, const unsigned short* __restrict__ Kp,
    const unsigned short* __restrict__ Vt, const int* __restrict__ mask,
    unsigned short* __restrict__ out)
{
    // K dbuf: [2][8 dchunk][128 k][16B] @ 0,16384
    // V dbuf: [2][16 kchunk][64 d][16B] @ 32768,49152
    // after loop: Oex f32[4][32][64] @ 0 ; lsum f32[4][2][32] @ 32768
    __shared__ __align__(16) char lds[65536];

    const int tid = threadIdx.x, lane = tid & 63, wave = tid >> 6;
    const int qb = wave >> 1, kh = wave & 1;
    const int r32 = lane & 31, hi = lane >> 5;
    const int bh = blockIdx.y, bb = bh >> 2, hh = bh & 3;
    const int q0 = blockIdx.x * 128;
    const size_t baseQ = (size_t)bh * CS * CDH;   // Q,K: [S][DH]
    const size_t baseT = (size_t)bh * CDH * CS;   // Vt:  [DH][S]

    // ---- Q fragments in registers (B-operand: col=q, k-chunk = dw*16+hi*8) ----
    const int qrow = q0 + qb * 32 + r32;
    bf16x8 qf[4];
    {
        const bool live = (mask[bb * CS + qrow] != 0);
        #pragma unroll
        for (int dw = 0; dw < 4; ++dw) {
            uint4 v = {0u, 0u, 0u, 0u};
            if (live) v = *(const uint4*)(Q + baseQ + (size_t)qrow * CDH + dw * 16 + hi * 8);
            qf[dw] = *(bf16x8*)&v;
        }
    }

    // staging: 1024 16B slots each for K and V; wave w covers slots [w*64+i*512 .. +63]
#define STAGE(BUF, KT) do {                                                             \
        _Pragma("unroll")                                                               \
        for (int i = 0; i < 2; ++i) {                                                   \
            const int slot0 = i * 512 + wave * 64;                                      \
            const int slot  = slot0 + lane;                                             \
            const int kw = slot >> 7, kk2 = slot & 127;                                 \
            GLOAD_LDS16(Kp + baseQ + (size_t)((KT) + kk2) * CDH + kw * 8,               \
                        lds + (BUF) * 16384 + slot0 * 16);                              \
            const int vc = slot >> 6, vd = slot & 63;                                   \
            GLOAD_LDS16(Vt + baseT + (size_t)vd * CS + (KT) + vc * 8,                   \
                        lds + 32768 + (BUF) * 16384 + slot0 * 16);                      \
        } } while (0)

    f32x16 o0 = zero16(), o1 = zero16();
    float psum = 0.f;

    STAGE(0, 0);
    __syncthreads();

    for (int t = 0; t < CS / 128; ++t) {
        const int buf = t & 1;
        const int kt = t * 128;
        if (t + 1 < CS / 128) STAGE(buf ^ 1, kt + 128);

        const char* kbase = lds + buf * 16384;
        const char* vbase = lds + 32768 + buf * 16384;

        // ---- QK^T swapped: sT[kb] = S^T[k=kh*64+kb*32+crow][q=r32] ----
        f32x16 sT0 = zero16(), sT1 = zero16();
        __builtin_amdgcn_s_setprio(1);
        #pragma unroll
        for (int dw = 0; dw < 4; ++dw) {
            const char* cb = kbase + (dw * 2 + hi) * 2048;
            bf16x8 k0 = *(const bf16x8*)(cb + (kh * 64 + r32) * 16);
            bf16x8 k1 = *(const bf16x8*)(cb + (kh * 64 + 32 + r32) * 16);
            sT0 = mfma32(k0, qf[dw], sT0);
            sT1 = mfma32(k1, qf[dw], sT1);
        }
        __builtin_amdgcn_s_setprio(0);

        // ---- p=exp2(s); pack; permlane -> PV A-frags; PV MFMA; no LDS for P ----
#define PROCKB(SREG, KB) do {                                                           \
            float p[16];                                                                \
            _Pragma("unroll")                                                           \
            for (int r = 0; r < 16; ++r) { p[r] = fexp2((SREG)[r]); psum += p[r]; }     \
            _Pragma("unroll")                                                           \
            for (int w = 0; w < 2; ++w) {                                               \
                unsigned int a01 = packbf(p[w*8+0], p[w*8+1]);                          \
                unsigned int a23 = packbf(p[w*8+2], p[w*8+3]);                          \
                unsigned int b01 = packbf(p[w*8+4], p[w*8+5]);                          \
                unsigned int b23 = packbf(p[w*8+6], p[w*8+7]);                          \
                unsigned int ap0, ap1, ap2, ap3;                                        \
                {                                                                       \
                    i32x2 s1 = __builtin_amdgcn_permlane32_swap((int)a01, (int)b01, false, false); \
                    i32x2 s2 = __builtin_amdgcn_permlane32_swap((int)a23, (int)b23, false, false); \
                    ap0 = (unsigned int)s1.x; ap2 = (unsigned int)s1.y;                 \
                    ap1 = (unsigned int)s2.x; ap3 = (unsigned int)s2.y;                 \
                }                                                                       \
                union { unsigned int u[4]; bf16x8 v; } apv;                             \
                apv.u[0] = ap0; apv.u[1] = ap1; apv.u[2] = ap2; apv.u[3] = ap3;         \
                const char* vb2 = vbase + ((kh * 4 + (KB) * 2 + w) * 2 + hi) * 1024;    \
                bf16x8 v0 = *(const bf16x8*)(vb2 + r32 * 16);                           \
                bf16x8 v1 = *(const bf16x8*)(vb2 + (32 + r32) * 16);                    \
                o0 = mfma32(apv.v, v0, o0);                                             \
                o1 = mfma32(apv.v, v1, o1);                                             \
            } } while (0)

        PROCKB(sT0, 0);
        PROCKB(sT1, 1);
#undef PROCKB

        __syncthreads();   // staged buf^1 complete (vmcnt drain) + all reads of buf done
    }

    // ---- end reduction: cross-hi psum, cross-kh O and l via LDS ----
    float ps = psum + __shfl_xor(psum, 32, 64);     // full k-half sum for q=qb*32+r32
    float* lsum = (float*)(lds + 32768);            // [4][2][32]
    float* Oex  = (float*)lds;                      // [4][32][64]
    if (lane < 32) lsum[(qb * 2 + kh) * 32 + r32] = ps;
    if (kh == 1) {
        #pragma unroll
        for (int r = 0; r < 16; ++r) {
            const int qr = (r & 3) + 8 * (r >> 2) + 4 * hi;
            Oex[(qb * 32 + qr) * 64 + r32]      = o0[r];
            Oex[(qb * 32 + qr) * 64 + 32 + r32] = o1[r];
        }
    }
    __syncthreads();
    if (kh == 0) {
        #pragma unroll
        for (int r = 0; r < 16; ++r) {
            const int qr = (r & 3) + 8 * (r >> 2) + 4 * hi;
            const float l = lsum[(qb * 2 + 0) * 32 + qr] + lsum[(qb * 2 + 1) * 32 + qr];
            const float inv = 1.0f / l;
            const float u0 = (o0[r] + Oex[(qb * 32 + qr) * 64 + r32]) * inv;
            const float u1 = (o1[r] + Oex[(qb * 32 + qr) * 64 + 32 + r32]) * inv;
            const size_t ob = (size_t)(bb * CS + q0 + qb * 32 + qr) * CH + hh * CDH;
            out[ob + r32]      = f2b(u0);
            out[ob + 32 + r32] = f2b(u1);
        }
    }
#undef STAGE
}

// ----------------------------------------------------------------------------------
extern "C" void kernel_launch(void* const* d_in, const int* in_sizes, int n_in,
                              void* d_out, int out_size, void* d_ws, size_t ws_size,
                              hipStream_t stream)
{
    const void* hidden = d_in[0];
    const void* Wq = d_in[1];  const void* bq = d_in[2];
    const void* Wk = d_in[3];  const void* bk = d_in[4];
    const void* Wv = d_in[5];  const void* bv = d_in[6];
    const void* Wo = d_in[7];  const void* bo = d_in[8];
    const void* W1 = d_in[9];  const void* b1 = d_in[10];
    const void* W2 = d_in[11]; const void* b2 = d_in[12];
    const void* ln1w = d_in[13]; const void* ln1b = d_in[14];
    const void* ln2w = d_in[15]; const void* ln2b = d_in[16];
    const int* mask = (const int*)d_in[17];

    char* ws = (char*)d_ws;
    const size_t KB = 1u << 10, MB = 1u << 20;
    int*            flag  = (int*)ws;
    float*          bqf   = (float*)(ws + 4*KB);
    float*          bkf   = (float*)(ws + 8*KB);
    float*          bvf   = (float*)(ws + 12*KB);
    float*          bof   = (float*)(ws + 16*KB);
    float*          b1f   = (float*)(ws + 20*KB);
    float*          b2f_  = (float*)(ws + 28*KB);
    float*          ln1wf = (float*)(ws + 32*KB);
    float*          ln1bf = (float*)(ws + 36*KB);
    float*          ln2wf = (float*)(ws + 40*KB);
    float*          ln2bf = (float*)(ws + 44*KB);
    unsigned short* Wqb   = (unsigned short*)(ws + 1*MB);
    unsigned short* Wkb   = (unsigned short*)(ws + 1*MB + 256*KB);
    unsigned short* Wvb   = (unsigned short*)(ws + 1*MB + 512*KB);
    unsigned short* Wob   = (unsigned short*)(ws + 1*MB + 768*KB);
    unsigned short* W1b   = (unsigned short*)(ws + 2*MB);
    unsigned short* W2b   = (unsigned short*)(ws + 2*MB + 512*KB);
    float*          hf32  = (float*)(ws + 3*MB);            // [T][H] f32, 16MB
    unsigned short* xhat  = (unsigned short*)(ws + 19*MB);  // 8MB
    unsigned short* qb    = (unsigned short*)(ws + 27*MB);  // 8MB
    unsigned short* kb    = (unsigned short*)(ws + 35*MB);  // 8MB
    unsigned short* vb    = (unsigned short*)(ws + 43*MB);  // 8MB
    unsigned short* attnb = xhat;                           // xhat dead after QKV
    float*          hid2f = (float*)(ws + 35*MB);           // 16MB over kb+vb (dead)
    unsigned short* vtb   = (unsigned short*)(ws + 51*MB);  // 8MB (pre-FFN lifetime)
    unsigned short* yhat  = qb;                             // qb dead after attn
    unsigned short* h1g   = (unsigned short*)(ws + 51*MB);  // [T][1024] bf16, 32MB

    dim3 blk(256);
    detect_kernel<<<1, blk, 0, stream>>>((const unsigned short*)hidden, flag);

    CvtArgs6 cw;
    cw.src[0]=Wq;  cw.dst[0]=Wqb; cw.n[0]=CH*CH;
    cw.src[1]=Wk;  cw.dst[1]=Wkb; cw.n[1]=CH*CH;
    cw.src[2]=Wv;  cw.dst[2]=Wvb; cw.n[2]=CH*CH;
    cw.src[3]=Wo;  cw.dst[3]=Wob; cw.n[3]=CH*CH;
    cw.src[4]=W1;  cw.dst[4]=W1b; cw.n[4]=4*CH*CH;
    cw.src[5]=W2;  cw.dst[5]=W2b; cw.n[5]=4*CH*CH;
    cvt_to_bf16_k<<<dim3(64, 6), blk, 0, stream>>>(flag, cw);

    CvtArgs11 cf;
    cf.src[0]=hidden; cf.dst[0]=hf32;  cf.n[0]=CT*CH;
    cf.src[1]=bq;     cf.dst[1]=bqf;   cf.n[1]=CH;
    cf.src[2]=bk;     cf.dst[2]=bkf;   cf.n[2]=CH;
    cf.src[3]=bv;     cf.dst[3]=bvf;   cf.n[3]=CH;
    cf.src[4]=bo;     cf.dst[4]=bof;   cf.n[4]=CH;
    cf.src[5]=b1;     cf.dst[5]=b1f;   cf.n[5]=4*CH;
    cf.src[6]=b2;     cf.dst[6]=b2f_;  cf.n[6]=CH;
    cf.src[7]=ln1w;   cf.dst[7]=ln1wf; cf.n[7]=CH;
    cf.src[8]=ln1b;   cf.dst[8]=ln1bf; cf.n[8]=CH;
    cf.src[9]=ln2w;   cf.dst[9]=ln2wf; cf.n[9]=CH;
    cf.src[10]=ln2b;  cf.dst[10]=ln2bf;cf.n[10]=CH;
    cvt_to_f32_k<<<dim3(512, 11), blk, 0, stream>>>(flag, cf);

    ln_kernel<<<CT / 4, blk, 0, stream>>>(hf32, ln1wf, ln1bf, xhat);
    k_qkv<<<dim3(CT / 128, CH / 128, 3), blk, 0, stream>>>(xhat, Wqb, bqf, qb,
                                                           Wkb, bkf, kb, Wvb, bvf, vb);
    vtrans_kernel<<<dim3(CS / 64, CB * CNH), blk, 0, stream>>>(vb, vtb);
    attn_kernel<<<dim3(CS / 128, CB * CNH), dim3(512), 0, stream>>>(qb, kb, vtb, mask, attnb);
    k_oproj<<<dim3(CT / 128, CH / 128), blk, 0, stream>>>(attnb, Wob, bof, hf32, hid2f);
    ln_kernel<<<CT / 4, blk, 0, stream>>>(hid2f, ln2wf, ln2bf, yhat);
    k_ffn1<<<dim3(CT / 128, (4 * CH) / 128), blk, 0, stream>>>(yhat, W1b, b1f, h1g);
    k_ffn2<<<dim3(CT / 128, CH / 128), blk, 0, stream>>>(h1g, W2b, b2f_, hid2f,
                                                         d_out, flag);
}